// Round 5
// baseline (508.984 us; speedup 1.0000x reference)
//
#include <hip/hip_runtime.h>

#define IN_DIM 128
#define HID 64
#define BN 128    // nodes per gemm block tile
#define KC 16     // gemm k-chunk
#define CH 16384  // edges per bucket chunk

__device__ __forceinline__ float relu(float v) { return v > 0.f ? v : 0.f; }

// ---- degree histogram (int); nt loads keep edge stream out of L2 ----
__global__ __launch_bounds__(256) void k_deg(const int* __restrict__ col,
                                             int* __restrict__ degi, int E) {
    int e = blockIdx.x * 256 + threadIdx.x;
    if (e < E) atomicAdd(&degi[__builtin_nontemporal_load(&col[e])], 1);
}

// ---- scan pass 1 (+ fused dinv): per-block exclusive scan of degi ----
__global__ __launch_bounds__(256) void k_scan1(const int* __restrict__ degi,
                                               float* __restrict__ dinv,
                                               int* __restrict__ start,
                                               int* __restrict__ bsum, int N) {
    __shared__ int s[256];
    const int tid = threadIdx.x;
    const int i = blockIdx.x * 256 + tid;
    const int v = (i < N) ? degi[i] : 0;
    if (i < N) dinv[i] = v > 0 ? rsqrtf((float)v) : 0.f;
    s[tid] = v;
    __syncthreads();
    for (int off = 1; off < 256; off <<= 1) {
        int t = (tid >= off) ? s[tid - off] : 0;
        __syncthreads();
        s[tid] += t;
        __syncthreads();
    }
    if (i < N) start[i] = s[tid] - v;
    if (tid == 255) bsum[blockIdx.x] = s[255];
}

// ---- scan pass 2: single block scans block sums (NB <= 512) ----
__global__ __launch_bounds__(512) void k_scan2(int* __restrict__ bsum, int NB) {
    __shared__ int s[512];
    const int tid = threadIdx.x;
    const int v = (tid < NB) ? bsum[tid] : 0;
    s[tid] = v;
    __syncthreads();
    for (int off = 1; off < 512; off <<= 1) {
        int t = (tid >= off) ? s[tid - off] : 0;
        __syncthreads();
        s[tid] += t;
        __syncthreads();
    }
    if (tid < NB) bsum[tid] = s[tid] - v;   // exclusive block offsets
}

// ---- scan pass 3: add block offsets; init cursor ----
__global__ __launch_bounds__(256) void k_scan3(int* __restrict__ start,
                                               const int* __restrict__ bsum,
                                               int* __restrict__ cursor, int N) {
    int i = blockIdx.x * 256 + threadIdx.x;
    if (i < N) {
        int v = start[i] + bsum[blockIdx.x];
        start[i] = v;
        cursor[i] = v;
    }
}

// ---- bucket edges by destination, range-partitioned ----
// block b: edge chunk b/8, keeps destinations in range (b&7) -> same-XCD
// (round-robin heuristic) so scatter lines merge in that XCD's L2.
// NT loads: keep the 8x-replayed edge stream from thrashing L2, which is
// what prevented dirty-line merging in round 4 (73 MB WRITE for 9.6 MB payload).
__global__ __launch_bounds__(256) void k_bucket(const int* __restrict__ row,
                                                const int* __restrict__ col,
                                                const float* __restrict__ dinv,
                                                int* __restrict__ cursor,
                                                int2* __restrict__ rw,
                                                int E, int RB, int N) {
    const int chunk = blockIdx.x >> 3;
    const int r = blockIdx.x & 7;
    const int lo = r * RB;
    const int hi = min(lo + RB, N);
    const int e1 = min(chunk * CH + CH, E);
    for (int e = chunk * CH + threadIdx.x; e < e1; e += 256) {
        const int c = __builtin_nontemporal_load(&col[e]);
        if (c >= lo && c < hi) {
            const int rr = __builtin_nontemporal_load(&row[e]);
            const int pos = atomicAdd(&cursor[c], 1);
            int2 v;
            v.x = rr;
            v.y = __float_as_int(dinv[rr] * dinv[c]);
            rw[pos] = v;
        }
    }
}

// ---- tiled dual GEMM: O1 = relu(Xcat @ W1 + B1), O2 = Xcat @ W2 ----
// LAYER 1: Xcat = XA (N x 128); LAYER 2: Xcat = [XA | relu(XB + CB)]
template <int LAYER>
__global__ __launch_bounds__(256) void k_gemm(const float* __restrict__ XA,
                                              const float* __restrict__ XB,
                                              const float* __restrict__ CB,
                                              const float* __restrict__ W1,
                                              const float* __restrict__ W2,
                                              const float* __restrict__ B1,
                                              float* __restrict__ O1,
                                              float* __restrict__ O2, int N) {
    __shared__ float Xs[KC][BN];   // 8 KB, [k][node]
    __shared__ float Ws[KC][128];  // 8 KB, [k][out] (0-63 W1, 64-127 W2)

    const int tid = threadIdx.x;
    const int n0 = blockIdx.x * BN;
    const int sn = tid >> 1;
    const int khalf = tid & 1;
    const int ng = min(n0 + sn, N - 1);
    const int wk = tid >> 5;
    const int wc = tid & 31;
    const int tn = tid & 15;
    const int tm = tid >> 4;

    float acc[8][8];
#pragma unroll
    for (int i = 0; i < 8; i++)
#pragma unroll
        for (int j = 0; j < 8; j++) acc[i][j] = 0.f;

    float4 xq0, xq1, wq0, wq1;
    int kb = khalf * 8;

    {
        const float* sx;
        if (LAYER == 1) sx = XA + (size_t)ng * IN_DIM + kb;
        else sx = (kb < 64) ? (XA + (size_t)ng * 64 + kb)
                            : (XB + (size_t)ng * 64 + (kb - 64));
        xq0 = *(const float4*)(sx + 0);
        xq1 = *(const float4*)(sx + 4);
        if (wc < 16) {
            wq0 = *(const float4*)(W1 + (size_t)wk * 64 + wc * 4);
            wq1 = *(const float4*)(W1 + (size_t)(wk + 8) * 64 + wc * 4);
        } else {
            wq0 = *(const float4*)(W2 + (size_t)wk * 64 + (wc - 16) * 4);
            wq1 = *(const float4*)(W2 + (size_t)(wk + 8) * 64 + (wc - 16) * 4);
        }
    }

    for (int c = 0; c < IN_DIM / KC; ++c) {
        __syncthreads();
        {
            float4 q0 = xq0, q1 = xq1;
            if (LAYER == 2) {
                const int kba = c * KC + kb;
                if (kba >= 64) {
                    const float4 c0 = *(const float4*)(CB + (kba - 64));
                    const float4 c1 = *(const float4*)(CB + (kba - 64) + 4);
                    q0.x = relu(q0.x + c0.x); q0.y = relu(q0.y + c0.y);
                    q0.z = relu(q0.z + c0.z); q0.w = relu(q0.w + c0.w);
                    q1.x = relu(q1.x + c1.x); q1.y = relu(q1.y + c1.y);
                    q1.z = relu(q1.z + c1.z); q1.w = relu(q1.w + c1.w);
                }
            }
            Xs[kb + 0][sn] = q0.x; Xs[kb + 1][sn] = q0.y;
            Xs[kb + 2][sn] = q0.z; Xs[kb + 3][sn] = q0.w;
            Xs[kb + 4][sn] = q1.x; Xs[kb + 5][sn] = q1.y;
            Xs[kb + 6][sn] = q1.z; Xs[kb + 7][sn] = q1.w;
            *(float4*)&Ws[wk][wc * 4] = wq0;
            *(float4*)&Ws[wk + 8][wc * 4] = wq1;
        }
        __syncthreads();
        if (c + 1 < IN_DIM / KC) {
            const int kn = (c + 1) * KC + kb;
            const float* sx;
            if (LAYER == 1) sx = XA + (size_t)ng * IN_DIM + kn;
            else sx = (kn < 64) ? (XA + (size_t)ng * 64 + kn)
                                : (XB + (size_t)ng * 64 + (kn - 64));
            xq0 = *(const float4*)(sx + 0);
            xq1 = *(const float4*)(sx + 4);
            const int k1 = (c + 1) * KC + wk, k2 = k1 + 8;
            if (wc < 16) {
                wq0 = *(const float4*)(W1 + (size_t)k1 * 64 + wc * 4);
                wq1 = *(const float4*)(W1 + (size_t)k2 * 64 + wc * 4);
            } else {
                wq0 = *(const float4*)(W2 + (size_t)k1 * 64 + (wc - 16) * 4);
                wq1 = *(const float4*)(W2 + (size_t)k2 * 64 + (wc - 16) * 4);
            }
        }
#pragma unroll 2
        for (int k = 0; k < KC; ++k) {
            const float4 aLo = *(const float4*)&Xs[k][tn * 4];
            const float4 aHi = *(const float4*)&Xs[k][64 + tn * 4];
            const float4 bLo = *(const float4*)&Ws[k][tm * 4];
            const float4 bHi = *(const float4*)&Ws[k][64 + tm * 4];
            const float b0 = bLo.x, b1 = bLo.y, b2 = bLo.z, b3 = bLo.w;
            const float b4 = bHi.x, b5 = bHi.y, b6 = bHi.z, b7 = bHi.w;
#define FMA_ROW(i, ai)                                                   \
    acc[i][0] += (ai) * b0; acc[i][1] += (ai) * b1;                      \
    acc[i][2] += (ai) * b2; acc[i][3] += (ai) * b3;                      \
    acc[i][4] += (ai) * b4; acc[i][5] += (ai) * b5;                      \
    acc[i][6] += (ai) * b6; acc[i][7] += (ai) * b7;
            FMA_ROW(0, aLo.x) FMA_ROW(1, aLo.y) FMA_ROW(2, aLo.z) FMA_ROW(3, aLo.w)
            FMA_ROW(4, aHi.x) FMA_ROW(5, aHi.y) FMA_ROW(6, aHi.z) FMA_ROW(7, aHi.w)
#undef FMA_ROW
        }
    }

    const float4 bb = *(const float4*)(B1 + tm * 4);
#pragma unroll
    for (int ih = 0; ih < 2; ++ih) {
#pragma unroll
        for (int i = 0; i < 4; ++i) {
            const int n = n0 + ih * 64 + tn * 4 + i;
            if (n < N) {
                const int r = ih * 4 + i;
                float4 o1v = make_float4(relu(acc[r][0] + bb.x), relu(acc[r][1] + bb.y),
                                         relu(acc[r][2] + bb.z), relu(acc[r][3] + bb.w));
                float4 o2v = make_float4(acc[r][4], acc[r][5], acc[r][6], acc[r][7]);
                *(float4*)(O1 + (size_t)n * 64 + tm * 4) = o1v;
                *(float4*)(O2 + (size_t)n * 64 + tm * 4) = o2v;
            }
        }
    }
}

// ---- CSR gather-aggregate, 64 features: wave per destination ----
__global__ __launch_bounds__(256) void k_gather64(const int* __restrict__ start,
                                                  const int* __restrict__ degi,
                                                  const int2* __restrict__ rw,
                                                  const float* __restrict__ H,
                                                  float* __restrict__ AGG, int N) {
    const int lane = threadIdx.x & 63;
    const int d = blockIdx.x * 4 + (threadIdx.x >> 6);
    if (d >= N) return;
    int s = start[d];
    const int e2 = s + degi[d];
    float acc = 0.f;
    for (; s + 3 < e2; s += 4) {
        const int2 a = rw[s], b = rw[s + 1], c = rw[s + 2], dd = rw[s + 3];
        acc += H[(size_t)a.x * 64 + lane] * __int_as_float(a.y);
        acc += H[(size_t)b.x * 64 + lane] * __int_as_float(b.y);
        acc += H[(size_t)c.x * 64 + lane] * __int_as_float(c.y);
        acc += H[(size_t)dd.x * 64 + lane] * __int_as_float(dd.y);
    }
    for (; s < e2; ++s) {
        const int2 a = rw[s];
        acc += H[(size_t)a.x * 64 + lane] * __int_as_float(a.y);
    }
    AGG[(size_t)d * 64 + lane] = acc;
}

// ---- combine: x7 = x5 + relu(agg2+cb2); out = x7.fc2w + fc2b + c3b; h3 = x7.c3w ----
__global__ __launch_bounds__(256) void k_combine(const float* __restrict__ X5,
                                                 const float* __restrict__ AGG2,
                                                 const float* __restrict__ CB2,
                                                 const float* __restrict__ FC2W,
                                                 const float* __restrict__ FC2B,
                                                 const float* __restrict__ C3W,
                                                 const float* __restrict__ C3B,
                                                 float* __restrict__ H3,
                                                 float* __restrict__ OUT, int N) {
    const int lane = threadIdx.x & 63;
    const int n = blockIdx.x * 4 + (threadIdx.x >> 6);
    if (n >= N) return;
    const size_t o = (size_t)n * 64 + lane;
    const float v = X5[o] + relu(AGG2[o] + CB2[lane]);
    float p9 = v * FC2W[lane];
    float p10 = v * C3W[lane];
#pragma unroll
    for (int s = 32; s >= 1; s >>= 1) {
        p9 += __shfl_xor(p9, s, 64);
        p10 += __shfl_xor(p10, s, 64);
    }
    if (lane == 0) {
        OUT[n] = p9 + FC2B[0] + C3B[0];
        H3[n] = p10;
    }
}

// ---- final CSR gather, 1 feature ----
__global__ __launch_bounds__(256) void k_gather1f(const int* __restrict__ start,
                                                  const int* __restrict__ degi,
                                                  const int2* __restrict__ rw,
                                                  const float* __restrict__ H3,
                                                  float* __restrict__ OUT, int N) {
    const int d = blockIdx.x * 256 + threadIdx.x;
    if (d >= N) return;
    int s = start[d];
    const int e2 = s + degi[d];
    float acc = 0.f;
    for (; s + 1 < e2; s += 2) {
        const int2 a = rw[s], b = rw[s + 1];
        acc += H3[a.x] * __int_as_float(a.y);
        acc += H3[b.x] * __int_as_float(b.y);
    }
    if (s < e2) {
        const int2 a = rw[s];
        acc += H3[a.x] * __int_as_float(a.y);
    }
    OUT[d] += acc;
}

extern "C" void kernel_launch(void* const* d_in, const int* in_sizes, int n_in,
                              void* d_out, int out_size, void* d_ws, size_t ws_size,
                              hipStream_t stream) {
    const float* x    = (const float*)d_in[0];
    const float* fcw  = (const float*)d_in[1];
    const float* fcb  = (const float*)d_in[2];
    const float* c1w  = (const float*)d_in[3];
    const float* c1b  = (const float*)d_in[4];
    const float* f1w  = (const float*)d_in[5];
    const float* f1b  = (const float*)d_in[6];
    const float* c2w  = (const float*)d_in[7];
    const float* c2b  = (const float*)d_in[8];
    const float* f2w  = (const float*)d_in[9];
    const float* f2b  = (const float*)d_in[10];
    const float* c3w  = (const float*)d_in[11];
    const float* c3b  = (const float*)d_in[12];
    const int*   ei   = (const int*)d_in[13];

    const int N = in_sizes[0] / IN_DIM;
    const int E = in_sizes[13] / 2;
    const int* row = ei;
    const int* col = ei + E;
    float* out = (float*)d_out;

    const size_t Npad = ((size_t)N + 127) & ~(size_t)127;
    const size_t Epad = ((size_t)E + 127) & ~(size_t)127;
    const size_t NF = (size_t)N * 64;
    int*   degi   = (int*)d_ws;                    // N
    float* dinv   = (float*)(degi + Npad);         // N
    int*   start  = (int*)(dinv + Npad);           // N
    int*   cursor = start + Npad;                  // N
    int*   bsum   = cursor + Npad;                 // 512
    int2*  rw     = (int2*)(bsum + 512);           // E (8B packed row+norm)
    float* x1     = (float*)(rw + Epad);           // N*64
    float* h1     = x1 + NF;                       // N*64
    float* agg1   = h1 + NF;                       // N*64
    float* x5     = agg1 + NF;                     // N*64
    float* h2     = h1;    // h1 dead after gather1
    float* agg2   = x1;    // x1 dead after gemm2
    float* h3     = agg1;  // agg1 dead after gemm2

    const int gE = (E + 255) / 256;
    const int gN = (N + 255) / 256;
    const int NB = (N + 255) / 256;
    const int gG = (N + BN - 1) / BN;
    const int gW = (N + 3) / 4;
    const int RB = (N + 7) / 8;
    const int nchunks = (E + CH - 1) / CH;

    // --- CSR build ---
    hipMemsetAsync(degi, 0, (size_t)N * sizeof(int), stream);
    k_deg<<<gE, 256, 0, stream>>>(col, degi, E);
    k_scan1<<<NB, 256, 0, stream>>>(degi, dinv, start, bsum, N);
    k_scan2<<<1, 512, 0, stream>>>(bsum, NB);
    k_scan3<<<NB, 256, 0, stream>>>(start, bsum, cursor, N);
    k_bucket<<<nchunks * 8, 256, 0, stream>>>(row, col, dinv, cursor, rw, E, RB, N);

    // --- layer 1 ---
    k_gemm<1><<<gG, 256, 0, stream>>>(x, nullptr, nullptr, fcw, c1w, fcb, x1, h1, N);
    k_gather64<<<gW, 256, 0, stream>>>(start, degi, rw, h1, agg1, N);

    // --- layer 2 ---
    k_gemm<2><<<gG, 256, 0, stream>>>(x1, agg1, c1b, f1w, c2w, f1b, x5, h2, N);
    k_gather64<<<gW, 256, 0, stream>>>(start, degi, rw, h2, agg2, N);

    // --- layer 3 ---
    k_combine<<<gW, 256, 0, stream>>>(x5, agg2, c2b, f2w, f2b, c3w, c3b, h3, out, N);
    k_gather1f<<<gN, 256, 0, stream>>>(start, degi, rw, h3, out, N);
}

// Round 6
// 413.259 us; speedup vs baseline: 1.2316x; 1.2316x over previous
//
#include <hip/hip_runtime.h>

#define IN_DIM 128
#define HID 64
#define BN 128      // nodes per gemm block tile
#define KC 16       // gemm k-chunk
#define RB_SHIFT 10 // 1024 nodes per dest-range
#define RB 1024
#define NBMAX 128   // max ranges (N <= 128K)
#define MAXBIN 16384 // capacity per range bin region (mean ~12.3K, +33 sigma)
#define PCH 2048    // edges per k_part block

__device__ __forceinline__ float relu(float v) { return v > 0.f ? v : 0.f; }

// ---- init bin cursors to fixed region bases ----
__global__ void k_initbins(int* __restrict__ binCursor, int NR) {
    if (threadIdx.x < NR) binCursor[threadIdx.x] = threadIdx.x * MAXBIN;
}

// ---- phase 1: partition edges into dest-ranges (block-aggregated reservations:
// ~64 global atomics per block instead of per-edge) ----
__global__ __launch_bounds__(256) void k_part(const int* __restrict__ row,
                                              const int* __restrict__ col,
                                              int* __restrict__ binCursor,
                                              int2* __restrict__ part, int E) {
    __shared__ int hist[NBMAX], gbase[NBMAX], lcur[NBMAX];
    const int tid = threadIdx.x;
    const int e0 = blockIdx.x * PCH;
    const int e1 = min(e0 + PCH, E);
    if (tid < NBMAX) { hist[tid] = 0; lcur[tid] = 0; }
    __syncthreads();
    int rr[8], cc[8];
#pragma unroll
    for (int j = 0; j < 8; j++) {
        const int e = e0 + j * 256 + tid;
        if (e < e1) {
            rr[j] = row[e];
            cc[j] = col[e];
            atomicAdd(&hist[cc[j] >> RB_SHIFT], 1);
        } else {
            cc[j] = -1;
        }
    }
    __syncthreads();
    if (tid < NBMAX && hist[tid] > 0)
        gbase[tid] = atomicAdd(&binCursor[tid], hist[tid]);
    __syncthreads();
#pragma unroll
    for (int j = 0; j < 8; j++) {
        if (cc[j] >= 0) {
            const int b = cc[j] >> RB_SHIFT;
            const int p = gbase[b] + atomicAdd(&lcur[b], 1);
            part[p] = make_int2(rr[j], cc[j]);
        }
    }
}

// ---- phase 2: per-range private histogram -> degi, dinv (no global atomics) ----
__global__ __launch_bounds__(256) void k_hist(const int* __restrict__ binCursor,
                                              const int2* __restrict__ part,
                                              int* __restrict__ degi,
                                              float* __restrict__ dinv, int N) {
    __shared__ int cnt[RB];
    const int b = blockIdx.x;
    const int lo = b << RB_SHIFT;
    const int tid = threadIdx.x;
    for (int i = tid; i < RB; i += 256) cnt[i] = 0;
    __syncthreads();
    const int base = b * MAXBIN;
    const int tot = binCursor[b] - base;
    for (int i = tid; i < tot; i += 256)
        atomicAdd(&cnt[part[base + i].y - lo], 1);
    __syncthreads();
    for (int i = tid; i < RB; i += 256) {
        const int n = lo + i;
        if (n < N) {
            const int d = cnt[i];
            degi[n] = d;
            dinv[n] = d > 0 ? rsqrtf((float)d) : 0.f;
        }
    }
}

// ---- scan pass 1: per-block exclusive scan of degi -> start, block sums ----
__global__ __launch_bounds__(256) void k_scan1(const int* __restrict__ degi,
                                               int* __restrict__ start,
                                               int* __restrict__ bsum, int N) {
    __shared__ int s[256];
    const int tid = threadIdx.x;
    const int i = blockIdx.x * 256 + tid;
    const int v = (i < N) ? degi[i] : 0;
    s[tid] = v;
    __syncthreads();
    for (int off = 1; off < 256; off <<= 1) {
        int t = (tid >= off) ? s[tid - off] : 0;
        __syncthreads();
        s[tid] += t;
        __syncthreads();
    }
    if (i < N) start[i] = s[tid] - v;
    if (tid == 255) bsum[blockIdx.x] = s[255];
}

// ---- scan pass 2: single block scans block sums (NB <= 512) ----
__global__ __launch_bounds__(512) void k_scan2(int* __restrict__ bsum, int NB) {
    __shared__ int s[512];
    const int tid = threadIdx.x;
    const int v = (tid < NB) ? bsum[tid] : 0;
    s[tid] = v;
    __syncthreads();
    for (int off = 1; off < 512; off <<= 1) {
        int t = (tid >= off) ? s[tid - off] : 0;
        __syncthreads();
        s[tid] += t;
        __syncthreads();
    }
    if (tid < NB) bsum[tid] = s[tid] - v;
}

// ---- scan pass 3: add block offsets ----
__global__ __launch_bounds__(256) void k_scan3(int* __restrict__ start,
                                               const int* __restrict__ bsum, int N) {
    int i = blockIdx.x * 256 + threadIdx.x;
    if (i < N) start[i] += bsum[blockIdx.x];
}

// ---- phase 3: per-range bucket with LDS cursors (no global atomics;
// rw writes confined to one ~100KB window per block -> single-XCD L2 merge) ----
__global__ __launch_bounds__(256) void k_bucket3(const int* __restrict__ binCursor,
                                                 const int2* __restrict__ part,
                                                 const int* __restrict__ start,
                                                 const float* __restrict__ dinv,
                                                 int2* __restrict__ rw, int N) {
    __shared__ int curs[RB];
    __shared__ float dv[RB];
    const int b = blockIdx.x;
    const int lo = b << RB_SHIFT;
    const int tid = threadIdx.x;
    for (int i = tid; i < RB; i += 256) {
        const int n = lo + i;
        curs[i] = (n < N) ? start[n] : 0;
        dv[i] = (n < N) ? dinv[n] : 0.f;
    }
    __syncthreads();
    const int base = b * MAXBIN;
    const int tot = binCursor[b] - base;
    for (int i = tid; i < tot; i += 256) {
        const int2 v = part[base + i];
        const int li = v.y - lo;
        const int pos = atomicAdd(&curs[li], 1);
        rw[pos] = make_int2(v.x, __float_as_int(dinv[v.x] * dv[li]));
    }
}

// ---- tiled dual GEMM: O1 = relu(Xcat @ W1 + B1), O2 = Xcat @ W2 ----
// LAYER 1: Xcat = XA (N x 128); LAYER 2: Xcat = [XA | relu(XB + CB)]
template <int LAYER>
__global__ __launch_bounds__(256) void k_gemm(const float* __restrict__ XA,
                                              const float* __restrict__ XB,
                                              const float* __restrict__ CB,
                                              const float* __restrict__ W1,
                                              const float* __restrict__ W2,
                                              const float* __restrict__ B1,
                                              float* __restrict__ O1,
                                              float* __restrict__ O2, int N) {
    __shared__ float Xs[KC][BN];
    __shared__ float Ws[KC][128];

    const int tid = threadIdx.x;
    const int n0 = blockIdx.x * BN;
    const int sn = tid >> 1;
    const int khalf = tid & 1;
    const int ng = min(n0 + sn, N - 1);
    const int wk = tid >> 5;
    const int wc = tid & 31;
    const int tn = tid & 15;
    const int tm = tid >> 4;

    float acc[8][8];
#pragma unroll
    for (int i = 0; i < 8; i++)
#pragma unroll
        for (int j = 0; j < 8; j++) acc[i][j] = 0.f;

    float4 xq0, xq1, wq0, wq1;
    int kb = khalf * 8;

    {
        const float* sx;
        if (LAYER == 1) sx = XA + (size_t)ng * IN_DIM + kb;
        else sx = (kb < 64) ? (XA + (size_t)ng * 64 + kb)
                            : (XB + (size_t)ng * 64 + (kb - 64));
        xq0 = *(const float4*)(sx + 0);
        xq1 = *(const float4*)(sx + 4);
        if (wc < 16) {
            wq0 = *(const float4*)(W1 + (size_t)wk * 64 + wc * 4);
            wq1 = *(const float4*)(W1 + (size_t)(wk + 8) * 64 + wc * 4);
        } else {
            wq0 = *(const float4*)(W2 + (size_t)wk * 64 + (wc - 16) * 4);
            wq1 = *(const float4*)(W2 + (size_t)(wk + 8) * 64 + (wc - 16) * 4);
        }
    }

    for (int c = 0; c < IN_DIM / KC; ++c) {
        __syncthreads();
        {
            float4 q0 = xq0, q1 = xq1;
            if (LAYER == 2) {
                const int kba = c * KC + kb;
                if (kba >= 64) {
                    const float4 c0 = *(const float4*)(CB + (kba - 64));
                    const float4 c1 = *(const float4*)(CB + (kba - 64) + 4);
                    q0.x = relu(q0.x + c0.x); q0.y = relu(q0.y + c0.y);
                    q0.z = relu(q0.z + c0.z); q0.w = relu(q0.w + c0.w);
                    q1.x = relu(q1.x + c1.x); q1.y = relu(q1.y + c1.y);
                    q1.z = relu(q1.z + c1.z); q1.w = relu(q1.w + c1.w);
                }
            }
            Xs[kb + 0][sn] = q0.x; Xs[kb + 1][sn] = q0.y;
            Xs[kb + 2][sn] = q0.z; Xs[kb + 3][sn] = q0.w;
            Xs[kb + 4][sn] = q1.x; Xs[kb + 5][sn] = q1.y;
            Xs[kb + 6][sn] = q1.z; Xs[kb + 7][sn] = q1.w;
            *(float4*)&Ws[wk][wc * 4] = wq0;
            *(float4*)&Ws[wk + 8][wc * 4] = wq1;
        }
        __syncthreads();
        if (c + 1 < IN_DIM / KC) {
            const int kn = (c + 1) * KC + kb;
            const float* sx;
            if (LAYER == 1) sx = XA + (size_t)ng * IN_DIM + kn;
            else sx = (kn < 64) ? (XA + (size_t)ng * 64 + kn)
                                : (XB + (size_t)ng * 64 + (kn - 64));
            xq0 = *(const float4*)(sx + 0);
            xq1 = *(const float4*)(sx + 4);
            const int k1 = (c + 1) * KC + wk, k2 = k1 + 8;
            if (wc < 16) {
                wq0 = *(const float4*)(W1 + (size_t)k1 * 64 + wc * 4);
                wq1 = *(const float4*)(W1 + (size_t)k2 * 64 + wc * 4);
            } else {
                wq0 = *(const float4*)(W2 + (size_t)k1 * 64 + (wc - 16) * 4);
                wq1 = *(const float4*)(W2 + (size_t)k2 * 64 + (wc - 16) * 4);
            }
        }
#pragma unroll 2
        for (int k = 0; k < KC; ++k) {
            const float4 aLo = *(const float4*)&Xs[k][tn * 4];
            const float4 aHi = *(const float4*)&Xs[k][64 + tn * 4];
            const float4 bLo = *(const float4*)&Ws[k][tm * 4];
            const float4 bHi = *(const float4*)&Ws[k][64 + tm * 4];
            const float b0 = bLo.x, b1 = bLo.y, b2 = bLo.z, b3 = bLo.w;
            const float b4 = bHi.x, b5 = bHi.y, b6 = bHi.z, b7 = bHi.w;
#define FMA_ROW(i, ai)                                                   \
    acc[i][0] += (ai) * b0; acc[i][1] += (ai) * b1;                      \
    acc[i][2] += (ai) * b2; acc[i][3] += (ai) * b3;                      \
    acc[i][4] += (ai) * b4; acc[i][5] += (ai) * b5;                      \
    acc[i][6] += (ai) * b6; acc[i][7] += (ai) * b7;
            FMA_ROW(0, aLo.x) FMA_ROW(1, aLo.y) FMA_ROW(2, aLo.z) FMA_ROW(3, aLo.w)
            FMA_ROW(4, aHi.x) FMA_ROW(5, aHi.y) FMA_ROW(6, aHi.z) FMA_ROW(7, aHi.w)
#undef FMA_ROW
        }
    }

    const float4 bb = *(const float4*)(B1 + tm * 4);
#pragma unroll
    for (int ih = 0; ih < 2; ++ih) {
#pragma unroll
        for (int i = 0; i < 4; ++i) {
            const int n = n0 + ih * 64 + tn * 4 + i;
            if (n < N) {
                const int r = ih * 4 + i;
                float4 o1v = make_float4(relu(acc[r][0] + bb.x), relu(acc[r][1] + bb.y),
                                         relu(acc[r][2] + bb.z), relu(acc[r][3] + bb.w));
                float4 o2v = make_float4(acc[r][4], acc[r][5], acc[r][6], acc[r][7]);
                *(float4*)(O1 + (size_t)n * 64 + tm * 4) = o1v;
                *(float4*)(O2 + (size_t)n * 64 + tm * 4) = o2v;
            }
        }
    }
}

// ---- CSR gather-aggregate, 64 features: wave per destination ----
__global__ __launch_bounds__(256) void k_gather64(const int* __restrict__ start,
                                                  const int* __restrict__ degi,
                                                  const int2* __restrict__ rw,
                                                  const float* __restrict__ H,
                                                  float* __restrict__ AGG, int N) {
    const int lane = threadIdx.x & 63;
    const int d = blockIdx.x * 4 + (threadIdx.x >> 6);
    if (d >= N) return;
    int s = start[d];
    const int e2 = s + degi[d];
    float acc = 0.f;
    for (; s + 3 < e2; s += 4) {
        const int2 a = rw[s], b = rw[s + 1], c = rw[s + 2], dd = rw[s + 3];
        acc += H[(size_t)a.x * 64 + lane] * __int_as_float(a.y);
        acc += H[(size_t)b.x * 64 + lane] * __int_as_float(b.y);
        acc += H[(size_t)c.x * 64 + lane] * __int_as_float(c.y);
        acc += H[(size_t)dd.x * 64 + lane] * __int_as_float(dd.y);
    }
    for (; s < e2; ++s) {
        const int2 a = rw[s];
        acc += H[(size_t)a.x * 64 + lane] * __int_as_float(a.y);
    }
    AGG[(size_t)d * 64 + lane] = acc;
}

// ---- combine: x7 = x5 + relu(agg2+cb2); out = x7.fc2w + fc2b + c3b; h3 = x7.c3w ----
__global__ __launch_bounds__(256) void k_combine(const float* __restrict__ X5,
                                                 const float* __restrict__ AGG2,
                                                 const float* __restrict__ CB2,
                                                 const float* __restrict__ FC2W,
                                                 const float* __restrict__ FC2B,
                                                 const float* __restrict__ C3W,
                                                 const float* __restrict__ C3B,
                                                 float* __restrict__ H3,
                                                 float* __restrict__ OUT, int N) {
    const int lane = threadIdx.x & 63;
    const int n = blockIdx.x * 4 + (threadIdx.x >> 6);
    if (n >= N) return;
    const size_t o = (size_t)n * 64 + lane;
    const float v = X5[o] + relu(AGG2[o] + CB2[lane]);
    float p9 = v * FC2W[lane];
    float p10 = v * C3W[lane];
#pragma unroll
    for (int s = 32; s >= 1; s >>= 1) {
        p9 += __shfl_xor(p9, s, 64);
        p10 += __shfl_xor(p10, s, 64);
    }
    if (lane == 0) {
        OUT[n] = p9 + FC2B[0] + C3B[0];
        H3[n] = p10;
    }
}

// ---- final CSR gather, 1 feature ----
__global__ __launch_bounds__(256) void k_gather1f(const int* __restrict__ start,
                                                  const int* __restrict__ degi,
                                                  const int2* __restrict__ rw,
                                                  const float* __restrict__ H3,
                                                  float* __restrict__ OUT, int N) {
    const int d = blockIdx.x * 256 + threadIdx.x;
    if (d >= N) return;
    int s = start[d];
    const int e2 = s + degi[d];
    float acc = 0.f;
    for (; s + 1 < e2; s += 2) {
        const int2 a = rw[s], b = rw[s + 1];
        acc += H3[a.x] * __int_as_float(a.y);
        acc += H3[b.x] * __int_as_float(b.y);
    }
    if (s < e2) {
        const int2 a = rw[s];
        acc += H3[a.x] * __int_as_float(a.y);
    }
    OUT[d] += acc;
}

extern "C" void kernel_launch(void* const* d_in, const int* in_sizes, int n_in,
                              void* d_out, int out_size, void* d_ws, size_t ws_size,
                              hipStream_t stream) {
    const float* x    = (const float*)d_in[0];
    const float* fcw  = (const float*)d_in[1];
    const float* fcb  = (const float*)d_in[2];
    const float* c1w  = (const float*)d_in[3];
    const float* c1b  = (const float*)d_in[4];
    const float* f1w  = (const float*)d_in[5];
    const float* f1b  = (const float*)d_in[6];
    const float* c2w  = (const float*)d_in[7];
    const float* c2b  = (const float*)d_in[8];
    const float* f2w  = (const float*)d_in[9];
    const float* f2b  = (const float*)d_in[10];
    const float* c3w  = (const float*)d_in[11];
    const float* c3b  = (const float*)d_in[12];
    const int*   ei   = (const int*)d_in[13];

    const int N = in_sizes[0] / IN_DIM;
    const int E = in_sizes[13] / 2;
    const int* row = ei;
    const int* col = ei + E;
    float* out = (float*)d_out;

    const int NR = (N + RB - 1) >> RB_SHIFT;      // dest-ranges (98 @ N=100K)

    const size_t Npad = ((size_t)N + 127) & ~(size_t)127;
    const size_t Epad = ((size_t)E + 127) & ~(size_t)127;
    const size_t NF = (size_t)N * 64;
    int*   binCur = (int*)d_ws;                    // NBMAX
    int*   degi   = binCur + NBMAX;                // N
    float* dinv   = (float*)(degi + Npad);         // N
    int*   start  = (int*)(dinv + Npad);           // N
    int*   bsum   = start + Npad;                  // 512
    int2*  part   = (int2*)(bsum + 512);           // NR*MAXBIN (12.8 MB)
    int2*  rw     = part + (size_t)NR * MAXBIN;    // E
    float* x1     = (float*)(rw + Epad);           // N*64
    float* h1     = x1 + NF;                       // N*64
    float* agg1   = h1 + NF;                       // N*64
    float* x5     = agg1 + NF;                     // N*64
    float* h2     = h1;    // h1 dead after gather1
    float* agg2   = x1;    // x1 dead after gemm2
    float* h3     = agg1;  // agg1 dead after gemm2

    const int gN = (N + 255) / 256;
    const int NB = (N + 255) / 256;
    const int gG = (N + BN - 1) / BN;
    const int gW = (N + 3) / 4;
    const int gP = (E + PCH - 1) / PCH;

    // --- CSR build (hierarchical, no per-edge global atomics) ---
    k_initbins<<<1, NBMAX, 0, stream>>>(binCur, NR);
    k_part<<<gP, 256, 0, stream>>>(row, col, binCur, part, E);
    k_hist<<<NR, 256, 0, stream>>>(binCur, part, degi, dinv, N);
    k_scan1<<<NB, 256, 0, stream>>>(degi, start, bsum, N);
    k_scan2<<<1, 512, 0, stream>>>(bsum, NB);
    k_scan3<<<NB, 256, 0, stream>>>(start, bsum, N);
    k_bucket3<<<NR, 256, 0, stream>>>(binCur, part, start, dinv, rw, N);

    // --- layer 1 ---
    k_gemm<1><<<gG, 256, 0, stream>>>(x, nullptr, nullptr, fcw, c1w, fcb, x1, h1, N);
    k_gather64<<<gW, 256, 0, stream>>>(start, degi, rw, h1, agg1, N);

    // --- layer 2 ---
    k_gemm<2><<<gG, 256, 0, stream>>>(x1, agg1, c1b, f1w, c2w, f1b, x5, h2, N);
    k_gather64<<<gW, 256, 0, stream>>>(start, degi, rw, h2, agg2, N);

    // --- layer 3 ---
    k_combine<<<gW, 256, 0, stream>>>(x5, agg2, c2b, f2w, f2b, c3w, c3b, h3, out, N);
    k_gather1f<<<gN, 256, 0, stream>>>(start, degi, rw, h3, out, N);
}

// Round 7
// 390.721 us; speedup vs baseline: 1.3027x; 1.0577x over previous
//
#include <hip/hip_runtime.h>

#define IN_DIM 128
#define HID 64
#define BN 128      // nodes per gemm block tile
#define KC 16       // gemm k-chunk
#define RB_SHIFT 10 // 1024 nodes per dest-range
#define RB 1024
#define NBMAX 128   // max ranges (N <= 128K)
#define MAXBIN 16384 // capacity per range bin region (mean ~12.3K)
#define PCH 2048    // edges per k_part block

__device__ __forceinline__ float relu(float v) { return v > 0.f ? v : 0.f; }

// fp32 -> bf16 with round-to-nearest-even
__device__ __forceinline__ unsigned short f2bf(float f) {
    unsigned u = __float_as_uint(f);
    u += 0x7FFFu + ((u >> 16) & 1u);
    return (unsigned short)(u >> 16);
}

// ---- init bin cursors to fixed region bases ----
__global__ void k_initbins(int* __restrict__ binCursor, int NR) {
    if (threadIdx.x < NR) binCursor[threadIdx.x] = threadIdx.x * MAXBIN;
}

// ---- phase 1: partition edges into dest-ranges; one LDS atomic per edge,
// one global atomic per bin per block ----
__global__ __launch_bounds__(256) void k_part(const int* __restrict__ row,
                                              const int* __restrict__ col,
                                              int* __restrict__ binCursor,
                                              int2* __restrict__ part, int E) {
    __shared__ int lcur[NBMAX], gbase[NBMAX];
    const int tid = threadIdx.x;
    const int e0 = blockIdx.x * PCH;
    const int cnt = min(PCH, E - e0);
    if (tid < NBMAX) lcur[tid] = 0;
    __syncthreads();
    int rr[8], cc[8], pp[8];
    if (cnt == PCH) {
#pragma unroll
        for (int h = 0; h < 2; h++) {
            const int4 c4 = *(const int4*)(col + e0 + h * 1024 + tid * 4);
            const int4 r4 = *(const int4*)(row + e0 + h * 1024 + tid * 4);
            cc[h * 4 + 0] = c4.x; cc[h * 4 + 1] = c4.y;
            cc[h * 4 + 2] = c4.z; cc[h * 4 + 3] = c4.w;
            rr[h * 4 + 0] = r4.x; rr[h * 4 + 1] = r4.y;
            rr[h * 4 + 2] = r4.z; rr[h * 4 + 3] = r4.w;
        }
    } else {
#pragma unroll
        for (int j = 0; j < 8; j++) {
            const int e = e0 + j * 256 + tid;
            if (e < e0 + cnt) { rr[j] = row[e]; cc[j] = col[e]; }
            else cc[j] = -1;
        }
    }
#pragma unroll
    for (int j = 0; j < 8; j++)
        if (cc[j] >= 0) pp[j] = atomicAdd(&lcur[cc[j] >> RB_SHIFT], 1);
    __syncthreads();
    if (tid < NBMAX && lcur[tid] > 0)
        gbase[tid] = atomicAdd(&binCursor[tid], lcur[tid]);
    __syncthreads();
#pragma unroll
    for (int j = 0; j < 8; j++)
        if (cc[j] >= 0)
            part[gbase[cc[j] >> RB_SHIFT] + pp[j]] = make_int2(rr[j], cc[j]);
}

// ---- phase 2: per-range private histogram -> degi, dinv ----
__global__ __launch_bounds__(256) void k_hist(const int* __restrict__ binCursor,
                                              const int2* __restrict__ part,
                                              int* __restrict__ degi,
                                              float* __restrict__ dinv, int N) {
    __shared__ int cnt[RB];
    const int b = blockIdx.x;
    const int lo = b << RB_SHIFT;
    const int tid = threadIdx.x;
    for (int i = tid; i < RB; i += 256) cnt[i] = 0;
    __syncthreads();
    const int base = b * MAXBIN;
    const int tot = binCursor[b] - base;
    for (int i = tid; i < tot; i += 256)
        atomicAdd(&cnt[part[base + i].y - lo], 1);
    __syncthreads();
    for (int i = tid; i < RB; i += 256) {
        const int n = lo + i;
        if (n < N) {
            const int d = cnt[i];
            degi[n] = d;
            dinv[n] = d > 0 ? rsqrtf((float)d) : 0.f;
        }
    }
}

// ---- scan pass 1 ----
__global__ __launch_bounds__(256) void k_scan1(const int* __restrict__ degi,
                                               int* __restrict__ start,
                                               int* __restrict__ bsum, int N) {
    __shared__ int s[256];
    const int tid = threadIdx.x;
    const int i = blockIdx.x * 256 + tid;
    const int v = (i < N) ? degi[i] : 0;
    s[tid] = v;
    __syncthreads();
    for (int off = 1; off < 256; off <<= 1) {
        int t = (tid >= off) ? s[tid - off] : 0;
        __syncthreads();
        s[tid] += t;
        __syncthreads();
    }
    if (i < N) start[i] = s[tid] - v;
    if (tid == 255) bsum[blockIdx.x] = s[255];
}

// ---- scan pass 2 ----
__global__ __launch_bounds__(512) void k_scan2(int* __restrict__ bsum, int NB) {
    __shared__ int s[512];
    const int tid = threadIdx.x;
    const int v = (tid < NB) ? bsum[tid] : 0;
    s[tid] = v;
    __syncthreads();
    for (int off = 1; off < 512; off <<= 1) {
        int t = (tid >= off) ? s[tid - off] : 0;
        __syncthreads();
        s[tid] += t;
        __syncthreads();
    }
    if (tid < NB) bsum[tid] = s[tid] - v;
}

// ---- scan pass 3 ----
__global__ __launch_bounds__(256) void k_scan3(int* __restrict__ start,
                                               const int* __restrict__ bsum, int N) {
    int i = blockIdx.x * 256 + threadIdx.x;
    if (i < N) start[i] += bsum[blockIdx.x];
}

// ---- phase 3: per-range bucket with LDS cursors ----
__global__ __launch_bounds__(256) void k_bucket3(const int* __restrict__ binCursor,
                                                 const int2* __restrict__ part,
                                                 const int* __restrict__ start,
                                                 const float* __restrict__ dinv,
                                                 int2* __restrict__ rw, int N) {
    __shared__ int curs[RB];
    __shared__ float dv[RB];
    const int b = blockIdx.x;
    const int lo = b << RB_SHIFT;
    const int tid = threadIdx.x;
    for (int i = tid; i < RB; i += 256) {
        const int n = lo + i;
        curs[i] = (n < N) ? start[n] : 0;
        dv[i] = (n < N) ? dinv[n] : 0.f;
    }
    __syncthreads();
    const int base = b * MAXBIN;
    const int tot = binCursor[b] - base;
    for (int i = tid; i < tot; i += 256) {
        const int2 v = part[base + i];
        const int li = v.y - lo;
        const int pos = atomicAdd(&curs[li], 1);
        rw[pos] = make_int2(v.x, __float_as_int(dinv[v.x] * dv[li]));
    }
}

// ---- tiled dual GEMM: O1 = relu(Xcat @ W1 + B1) fp32, O2 = Xcat @ W2 in BF16 ----
// LAYER 1: Xcat = XA (N x 128); LAYER 2: Xcat = [XA | relu(XB + CB)]
template <int LAYER>
__global__ __launch_bounds__(256) void k_gemm(const float* __restrict__ XA,
                                              const float* __restrict__ XB,
                                              const float* __restrict__ CB,
                                              const float* __restrict__ W1,
                                              const float* __restrict__ W2,
                                              const float* __restrict__ B1,
                                              float* __restrict__ O1,
                                              unsigned short* __restrict__ O2,
                                              int N) {
    __shared__ float Xs[KC][BN];
    __shared__ float Ws[KC][128];

    const int tid = threadIdx.x;
    const int n0 = blockIdx.x * BN;
    const int sn = tid >> 1;
    const int khalf = tid & 1;
    const int ng = min(n0 + sn, N - 1);
    const int wk = tid >> 5;
    const int wc = tid & 31;
    const int tn = tid & 15;
    const int tm = tid >> 4;

    float acc[8][8];
#pragma unroll
    for (int i = 0; i < 8; i++)
#pragma unroll
        for (int j = 0; j < 8; j++) acc[i][j] = 0.f;

    float4 xq0, xq1, wq0, wq1;
    int kb = khalf * 8;

    {
        const float* sx;
        if (LAYER == 1) sx = XA + (size_t)ng * IN_DIM + kb;
        else sx = (kb < 64) ? (XA + (size_t)ng * 64 + kb)
                            : (XB + (size_t)ng * 64 + (kb - 64));
        xq0 = *(const float4*)(sx + 0);
        xq1 = *(const float4*)(sx + 4);
        if (wc < 16) {
            wq0 = *(const float4*)(W1 + (size_t)wk * 64 + wc * 4);
            wq1 = *(const float4*)(W1 + (size_t)(wk + 8) * 64 + wc * 4);
        } else {
            wq0 = *(const float4*)(W2 + (size_t)wk * 64 + (wc - 16) * 4);
            wq1 = *(const float4*)(W2 + (size_t)(wk + 8) * 64 + (wc - 16) * 4);
        }
    }

    for (int c = 0; c < IN_DIM / KC; ++c) {
        __syncthreads();
        {
            float4 q0 = xq0, q1 = xq1;
            if (LAYER == 2) {
                const int kba = c * KC + kb;
                if (kba >= 64) {
                    const float4 c0 = *(const float4*)(CB + (kba - 64));
                    const float4 c1 = *(const float4*)(CB + (kba - 64) + 4);
                    q0.x = relu(q0.x + c0.x); q0.y = relu(q0.y + c0.y);
                    q0.z = relu(q0.z + c0.z); q0.w = relu(q0.w + c0.w);
                    q1.x = relu(q1.x + c1.x); q1.y = relu(q1.y + c1.y);
                    q1.z = relu(q1.z + c1.z); q1.w = relu(q1.w + c1.w);
                }
            }
            Xs[kb + 0][sn] = q0.x; Xs[kb + 1][sn] = q0.y;
            Xs[kb + 2][sn] = q0.z; Xs[kb + 3][sn] = q0.w;
            Xs[kb + 4][sn] = q1.x; Xs[kb + 5][sn] = q1.y;
            Xs[kb + 6][sn] = q1.z; Xs[kb + 7][sn] = q1.w;
            *(float4*)&Ws[wk][wc * 4] = wq0;
            *(float4*)&Ws[wk + 8][wc * 4] = wq1;
        }
        __syncthreads();
        if (c + 1 < IN_DIM / KC) {
            const int kn = (c + 1) * KC + kb;
            const float* sx;
            if (LAYER == 1) sx = XA + (size_t)ng * IN_DIM + kn;
            else sx = (kn < 64) ? (XA + (size_t)ng * 64 + kn)
                                : (XB + (size_t)ng * 64 + (kn - 64));
            xq0 = *(const float4*)(sx + 0);
            xq1 = *(const float4*)(sx + 4);
            const int k1 = (c + 1) * KC + wk, k2 = k1 + 8;
            if (wc < 16) {
                wq0 = *(const float4*)(W1 + (size_t)k1 * 64 + wc * 4);
                wq1 = *(const float4*)(W1 + (size_t)k2 * 64 + wc * 4);
            } else {
                wq0 = *(const float4*)(W2 + (size_t)k1 * 64 + (wc - 16) * 4);
                wq1 = *(const float4*)(W2 + (size_t)k2 * 64 + (wc - 16) * 4);
            }
        }
#pragma unroll 2
        for (int k = 0; k < KC; ++k) {
            const float4 aLo = *(const float4*)&Xs[k][tn * 4];
            const float4 aHi = *(const float4*)&Xs[k][64 + tn * 4];
            const float4 bLo = *(const float4*)&Ws[k][tm * 4];
            const float4 bHi = *(const float4*)&Ws[k][64 + tm * 4];
            const float b0 = bLo.x, b1 = bLo.y, b2 = bLo.z, b3 = bLo.w;
            const float b4 = bHi.x, b5 = bHi.y, b6 = bHi.z, b7 = bHi.w;
#define FMA_ROW(i, ai)                                                   \
    acc[i][0] += (ai) * b0; acc[i][1] += (ai) * b1;                      \
    acc[i][2] += (ai) * b2; acc[i][3] += (ai) * b3;                      \
    acc[i][4] += (ai) * b4; acc[i][5] += (ai) * b5;                      \
    acc[i][6] += (ai) * b6; acc[i][7] += (ai) * b7;
            FMA_ROW(0, aLo.x) FMA_ROW(1, aLo.y) FMA_ROW(2, aLo.z) FMA_ROW(3, aLo.w)
            FMA_ROW(4, aHi.x) FMA_ROW(5, aHi.y) FMA_ROW(6, aHi.z) FMA_ROW(7, aHi.w)
#undef FMA_ROW
        }
    }

    const float4 bb = *(const float4*)(B1 + tm * 4);
#pragma unroll
    for (int ih = 0; ih < 2; ++ih) {
#pragma unroll
        for (int i = 0; i < 4; ++i) {
            const int n = n0 + ih * 64 + tn * 4 + i;
            if (n < N) {
                const int r = ih * 4 + i;
                float4 o1v = make_float4(relu(acc[r][0] + bb.x), relu(acc[r][1] + bb.y),
                                         relu(acc[r][2] + bb.z), relu(acc[r][3] + bb.w));
                ushort4 o2v;
                o2v.x = f2bf(acc[r][4]); o2v.y = f2bf(acc[r][5]);
                o2v.z = f2bf(acc[r][6]); o2v.w = f2bf(acc[r][7]);
                *(float4*)(O1 + (size_t)n * 64 + tm * 4) = o1v;
                *(ushort4*)(O2 + (size_t)n * 64 + tm * 4) = o2v;
            }
        }
    }
}

// ---- CSR gather-aggregate, bf16 H (128 B rows): half-wave per destination ----
// lane l handles features 2l, 2l+1; one fully-coalesced 128 B row load/edge.
__global__ __launch_bounds__(256) void k_gather64(const int* __restrict__ start,
                                                  const int* __restrict__ degi,
                                                  const int2* __restrict__ rw,
                                                  const unsigned short* __restrict__ H,
                                                  float* __restrict__ AGG, int N) {
    const int l = threadIdx.x & 31;
    const int d = blockIdx.x * 8 + (threadIdx.x >> 5);
    if (d >= N) return;
    int s = start[d];
    const int e2 = s + degi[d];
    float a0 = 0.f, a1 = 0.f;
    for (; s + 1 < e2; s += 2) {
        const int2 ea = rw[s], eb = rw[s + 1];
        const unsigned ua = *(const unsigned*)(H + (size_t)ea.x * 64 + l * 2);
        const unsigned ub = *(const unsigned*)(H + (size_t)eb.x * 64 + l * 2);
        const float wa = __int_as_float(ea.y), wb = __int_as_float(eb.y);
        a0 += wa * __uint_as_float(ua << 16);
        a1 += wa * __uint_as_float(ua & 0xFFFF0000u);
        a0 += wb * __uint_as_float(ub << 16);
        a1 += wb * __uint_as_float(ub & 0xFFFF0000u);
    }
    if (s < e2) {
        const int2 ea = rw[s];
        const unsigned ua = *(const unsigned*)(H + (size_t)ea.x * 64 + l * 2);
        const float wa = __int_as_float(ea.y);
        a0 += wa * __uint_as_float(ua << 16);
        a1 += wa * __uint_as_float(ua & 0xFFFF0000u);
    }
    *(float2*)(AGG + (size_t)d * 64 + l * 2) = make_float2(a0, a1);
}

// ---- combine: x7 = x5 + relu(agg2+cb2); out = x7.fc2w + fc2b + c3b; h3 = x7.c3w ----
__global__ __launch_bounds__(256) void k_combine(const float* __restrict__ X5,
                                                 const float* __restrict__ AGG2,
                                                 const float* __restrict__ CB2,
                                                 const float* __restrict__ FC2W,
                                                 const float* __restrict__ FC2B,
                                                 const float* __restrict__ C3W,
                                                 const float* __restrict__ C3B,
                                                 float* __restrict__ H3,
                                                 float* __restrict__ OUT, int N) {
    const int lane = threadIdx.x & 63;
    const int n = blockIdx.x * 4 + (threadIdx.x >> 6);
    if (n >= N) return;
    const size_t o = (size_t)n * 64 + lane;
    const float v = X5[o] + relu(AGG2[o] + CB2[lane]);
    float p9 = v * FC2W[lane];
    float p10 = v * C3W[lane];
#pragma unroll
    for (int s = 32; s >= 1; s >>= 1) {
        p9 += __shfl_xor(p9, s, 64);
        p10 += __shfl_xor(p10, s, 64);
    }
    if (lane == 0) {
        OUT[n] = p9 + FC2B[0] + C3B[0];
        H3[n] = p10;
    }
}

// ---- final CSR gather, 1 feature ----
__global__ __launch_bounds__(256) void k_gather1f(const int* __restrict__ start,
                                                  const int* __restrict__ degi,
                                                  const int2* __restrict__ rw,
                                                  const float* __restrict__ H3,
                                                  float* __restrict__ OUT, int N) {
    const int d = blockIdx.x * 256 + threadIdx.x;
    if (d >= N) return;
    int s = start[d];
    const int e2 = s + degi[d];
    float acc = 0.f;
    for (; s + 1 < e2; s += 2) {
        const int2 a = rw[s], b = rw[s + 1];
        acc += H3[a.x] * __int_as_float(a.y);
        acc += H3[b.x] * __int_as_float(b.y);
    }
    if (s < e2) {
        const int2 a = rw[s];
        acc += H3[a.x] * __int_as_float(a.y);
    }
    OUT[d] += acc;
}

extern "C" void kernel_launch(void* const* d_in, const int* in_sizes, int n_in,
                              void* d_out, int out_size, void* d_ws, size_t ws_size,
                              hipStream_t stream) {
    const float* x    = (const float*)d_in[0];
    const float* fcw  = (const float*)d_in[1];
    const float* fcb  = (const float*)d_in[2];
    const float* c1w  = (const float*)d_in[3];
    const float* c1b  = (const float*)d_in[4];
    const float* f1w  = (const float*)d_in[5];
    const float* f1b  = (const float*)d_in[6];
    const float* c2w  = (const float*)d_in[7];
    const float* c2b  = (const float*)d_in[8];
    const float* f2w  = (const float*)d_in[9];
    const float* f2b  = (const float*)d_in[10];
    const float* c3w  = (const float*)d_in[11];
    const float* c3b  = (const float*)d_in[12];
    const int*   ei   = (const int*)d_in[13];

    const int N = in_sizes[0] / IN_DIM;
    const int E = in_sizes[13] / 2;
    const int* row = ei;
    const int* col = ei + E;
    float* out = (float*)d_out;

    const int NR = (N + RB - 1) >> RB_SHIFT;

    const size_t Npad = ((size_t)N + 127) & ~(size_t)127;
    const size_t Epad = ((size_t)E + 127) & ~(size_t)127;
    const size_t NF = (size_t)N * 64;
    int*   binCur = (int*)d_ws;                          // NBMAX
    int*   degi   = binCur + NBMAX;                      // N
    float* dinv   = (float*)(degi + Npad);               // N
    int*   start  = (int*)(dinv + Npad);                 // N
    int*   bsum   = start + Npad;                        // 512
    int2*  part   = (int2*)(bsum + 512);                 // NR*MAXBIN
    int2*  rw     = part + (size_t)NR * MAXBIN;          // E
    float* x1     = (float*)(rw + Epad);                 // N*64 f32
    unsigned short* h1 = (unsigned short*)(x1 + NF);     // N*64 bf16
    float* agg1   = (float*)(h1 + NF);                   // N*64 f32
    float* x5     = agg1 + NF;                           // N*64 f32
    unsigned short* h2 = h1;   // h1 dead after gather1
    float* agg2   = x1;        // x1 dead after gemm2
    float* h3     = agg1;      // agg1 dead after gemm2

    const int gN = (N + 255) / 256;
    const int NB = (N + 255) / 256;
    const int gG = (N + BN - 1) / BN;
    const int gW = (N + 7) / 8;
    const int gC = (N + 3) / 4;
    const int gP = (E + PCH - 1) / PCH;

    // --- CSR build (hierarchical, no per-edge global atomics) ---
    k_initbins<<<1, NBMAX, 0, stream>>>(binCur, NR);
    k_part<<<gP, 256, 0, stream>>>(row, col, binCur, part, E);
    k_hist<<<NR, 256, 0, stream>>>(binCur, part, degi, dinv, N);
    k_scan1<<<NB, 256, 0, stream>>>(degi, start, bsum, N);
    k_scan2<<<1, 512, 0, stream>>>(bsum, NB);
    k_scan3<<<NB, 256, 0, stream>>>(start, bsum, N);
    k_bucket3<<<NR, 256, 0, stream>>>(binCur, part, start, dinv, rw, N);

    // --- layer 1 ---
    k_gemm<1><<<gG, 256, 0, stream>>>(x, nullptr, nullptr, fcw, c1w, fcb, x1, h1, N);
    k_gather64<<<gW, 256, 0, stream>>>(start, degi, rw, h1, agg1, N);

    // --- layer 2 ---
    k_gemm<2><<<gG, 256, 0, stream>>>(x1, agg1, c1b, f1w, c2w, f1b, x5, h2, N);
    k_gather64<<<gW, 256, 0, stream>>>(start, degi, rw, h2, agg2, N);

    // --- layer 3 ---
    k_combine<<<gC, 256, 0, stream>>>(x5, agg2, c2b, f2w, f2b, c3w, c3b, h3, out, N);
    k_gather1f<<<gN, 256, 0, stream>>>(start, degi, rw, h3, out, N);
}

// Round 8
// 343.099 us; speedup vs baseline: 1.4835x; 1.1388x over previous
//
#include <hip/hip_runtime.h>

#define IN_DIM 128
#define HID 64
#define RB_SHIFT 10 // 1024 nodes per dest-range
#define RB 1024
#define NBMAX 128   // max ranges (N <= 128K)
#define MAXBIN 16384 // capacity per range bin region (mean ~12.3K)
#define PCH 2048    // edges per k_part block

typedef short bf16x8 __attribute__((ext_vector_type(8)));
typedef float f32x4  __attribute__((ext_vector_type(4)));

__device__ __forceinline__ float relu(float v) { return v > 0.f ? v : 0.f; }

// fp32 -> bf16 with round-to-nearest-even
__device__ __forceinline__ unsigned short f2bf(float f) {
    unsigned u = __float_as_uint(f);
    u += 0x7FFFu + ((u >> 16) & 1u);
    return (unsigned short)(u >> 16);
}

// ---- init bin cursors to fixed region bases ----
__global__ void k_initbins(int* __restrict__ binCursor, int NR) {
    if (threadIdx.x < NR) binCursor[threadIdx.x] = threadIdx.x * MAXBIN;
}

// ---- one-time weight repack into MFMA B-fragment order ----
// Wt[layer][kc][c][lane][j] bf16 : B[k=kc*32+(lane>>4)*8+j][col=c*16+(lane&15)]
// layer0: (fcw|c1w), layer1: (f1w|c2w); each lane's frag = contiguous 16 B.
__global__ __launch_bounds__(256) void k_wprep(const float* __restrict__ W1a,
                                               const float* __restrict__ W2a,
                                               const float* __restrict__ W1b,
                                               const float* __restrict__ W2b,
                                               unsigned short* __restrict__ Wt) {
    const int t = blockIdx.x * 256 + threadIdx.x;   // (layer,kc,c,lane)
    if (t >= 2 * 4 * 8 * 64) return;
    const int lane = t & 63;
    const int c = (t >> 6) & 7;
    const int kc = (t >> 9) & 3;
    const int layer = t >> 11;
    const int col = c * 16 + (lane & 15);
    const int k0 = kc * 32 + (lane >> 4) * 8;
    const float* W1 = layer ? W1b : W1a;
    const float* W2 = layer ? W2b : W2a;
    const float* src = (col < 64) ? (W1 + col) : (W2 + (col - 64));
    unsigned short v[8];
#pragma unroll
    for (int j = 0; j < 8; j++) v[j] = f2bf(src[(size_t)(k0 + j) * 64]);
    *(ushort4*)(Wt + (size_t)t * 8) = make_ushort4(v[0], v[1], v[2], v[3]);
    *(ushort4*)(Wt + (size_t)t * 8 + 4) = make_ushort4(v[4], v[5], v[6], v[7]);
}

// ---- phase 1: partition edges into dest-ranges ----
__global__ __launch_bounds__(256) void k_part(const int* __restrict__ row,
                                              const int* __restrict__ col,
                                              int* __restrict__ binCursor,
                                              int2* __restrict__ part, int E) {
    __shared__ int lcur[NBMAX], gbase[NBMAX];
    const int tid = threadIdx.x;
    const int e0 = blockIdx.x * PCH;
    const int cnt = min(PCH, E - e0);
    if (tid < NBMAX) lcur[tid] = 0;
    __syncthreads();
    int rr[8], cc[8], pp[8];
    if (cnt == PCH) {
#pragma unroll
        for (int h = 0; h < 2; h++) {
            const int4 c4 = *(const int4*)(col + e0 + h * 1024 + tid * 4);
            const int4 r4 = *(const int4*)(row + e0 + h * 1024 + tid * 4);
            cc[h * 4 + 0] = c4.x; cc[h * 4 + 1] = c4.y;
            cc[h * 4 + 2] = c4.z; cc[h * 4 + 3] = c4.w;
            rr[h * 4 + 0] = r4.x; rr[h * 4 + 1] = r4.y;
            rr[h * 4 + 2] = r4.z; rr[h * 4 + 3] = r4.w;
        }
    } else {
#pragma unroll
        for (int j = 0; j < 8; j++) {
            const int e = e0 + j * 256 + tid;
            if (e < e0 + cnt) { rr[j] = row[e]; cc[j] = col[e]; }
            else cc[j] = -1;
        }
    }
#pragma unroll
    for (int j = 0; j < 8; j++)
        if (cc[j] >= 0) pp[j] = atomicAdd(&lcur[cc[j] >> RB_SHIFT], 1);
    __syncthreads();
    if (tid < NBMAX && lcur[tid] > 0)
        gbase[tid] = atomicAdd(&binCursor[tid], lcur[tid]);
    __syncthreads();
#pragma unroll
    for (int j = 0; j < 8; j++)
        if (cc[j] >= 0)
            part[gbase[cc[j] >> RB_SHIFT] + pp[j]] = make_int2(rr[j], cc[j]);
}

// ---- phase 2: per-range private histogram -> degi, dinv ----
__global__ __launch_bounds__(256) void k_hist(const int* __restrict__ binCursor,
                                              const int2* __restrict__ part,
                                              int* __restrict__ degi,
                                              float* __restrict__ dinv, int N) {
    __shared__ int cnt[RB];
    const int b = blockIdx.x;
    const int lo = b << RB_SHIFT;
    const int tid = threadIdx.x;
    for (int i = tid; i < RB; i += 256) cnt[i] = 0;
    __syncthreads();
    const int base = b * MAXBIN;
    const int tot = binCursor[b] - base;
    for (int i = tid; i < tot; i += 256)
        atomicAdd(&cnt[part[base + i].y - lo], 1);
    __syncthreads();
    for (int i = tid; i < RB; i += 256) {
        const int n = lo + i;
        if (n < N) {
            const int d = cnt[i];
            degi[n] = d;
            dinv[n] = d > 0 ? rsqrtf((float)d) : 0.f;
        }
    }
}

// ---- scan pass 1 ----
__global__ __launch_bounds__(256) void k_scan1(const int* __restrict__ degi,
                                               int* __restrict__ start,
                                               int* __restrict__ bsum, int N) {
    __shared__ int s[256];
    const int tid = threadIdx.x;
    const int i = blockIdx.x * 256 + tid;
    const int v = (i < N) ? degi[i] : 0;
    s[tid] = v;
    __syncthreads();
    for (int off = 1; off < 256; off <<= 1) {
        int t = (tid >= off) ? s[tid - off] : 0;
        __syncthreads();
        s[tid] += t;
        __syncthreads();
    }
    if (i < N) start[i] = s[tid] - v;
    if (tid == 255) bsum[blockIdx.x] = s[255];
}

// ---- scan pass 2 ----
__global__ __launch_bounds__(512) void k_scan2(int* __restrict__ bsum, int NB) {
    __shared__ int s[512];
    const int tid = threadIdx.x;
    const int v = (tid < NB) ? bsum[tid] : 0;
    s[tid] = v;
    __syncthreads();
    for (int off = 1; off < 512; off <<= 1) {
        int t = (tid >= off) ? s[tid - off] : 0;
        __syncthreads();
        s[tid] += t;
        __syncthreads();
    }
    if (tid < NB) bsum[tid] = s[tid] - v;
}

// ---- scan pass 3 ----
__global__ __launch_bounds__(256) void k_scan3(int* __restrict__ start,
                                               const int* __restrict__ bsum, int N) {
    int i = blockIdx.x * 256 + threadIdx.x;
    if (i < N) start[i] += bsum[blockIdx.x];
}

// ---- phase 3: per-range bucket with LDS cursors ----
__global__ __launch_bounds__(256) void k_bucket3(const int* __restrict__ binCursor,
                                                 const int2* __restrict__ part,
                                                 const int* __restrict__ start,
                                                 const float* __restrict__ dinv,
                                                 int2* __restrict__ rw, int N) {
    __shared__ int curs[RB];
    __shared__ float dv[RB];
    const int b = blockIdx.x;
    const int lo = b << RB_SHIFT;
    const int tid = threadIdx.x;
    for (int i = tid; i < RB; i += 256) {
        const int n = lo + i;
        curs[i] = (n < N) ? start[n] : 0;
        dv[i] = (n < N) ? dinv[n] : 0.f;
    }
    __syncthreads();
    const int base = b * MAXBIN;
    const int tot = binCursor[b] - base;
    for (int i = tid; i < tot; i += 256) {
        const int2 v = part[base + i];
        const int li = v.y - lo;
        const int pos = atomicAdd(&curs[li], 1);
        rw[pos] = make_int2(v.x, __float_as_int(dinv[v.x] * dv[li]));
    }
}

// ---- MFMA dual GEMM: O1 = relu(Xcat @ W1 + B1) fp32, O2 = Xcat @ W2 bf16 ----
// LDS-free: wave = 16 nodes x 128 cols; A-frags from global fp32 (cvt to bf16),
// B-frags = one 16B L2-hot load per (kc,c) from the k_wprep repack.
// A layout: A[m=lane&15][k=quad*8+j]; C/D: col=lane&15, row=quad*4+reg.
template <int LAYER>
__global__ __launch_bounds__(256) void k_gemm(const float* __restrict__ XA,
                                              const float* __restrict__ XB,
                                              const float* __restrict__ CB,
                                              const unsigned short* __restrict__ Wt,
                                              const float* __restrict__ B1,
                                              float* __restrict__ O1,
                                              unsigned short* __restrict__ O2,
                                              int N) {
    const int tid = threadIdx.x;
    const int wave = tid >> 6;
    const int lane = tid & 63;
    const int quad = lane >> 4;
    const int lm = lane & 15;
    const int n0 = blockIdx.x * 64 + wave * 16;
    if (n0 >= N) return;
    const int nrow = min(n0 + lm, N - 1);

    f32x4 acc[8];
#pragma unroll
    for (int c = 0; c < 8; c++) acc[c] = (f32x4){0.f, 0.f, 0.f, 0.f};

#pragma unroll
    for (int kc = 0; kc < 4; kc++) {
        const int k0 = kc * 32 + quad * 8;
        float4 q0, q1;
        if (LAYER == 1) {
            const float* s = XA + (size_t)nrow * IN_DIM + k0;
            q0 = *(const float4*)s;
            q1 = *(const float4*)(s + 4);
        } else {
            if (kc < 2) {   // first half of concat: x1 (fp32)
                const float* s = XA + (size_t)nrow * 64 + k0;
                q0 = *(const float4*)s;
                q1 = *(const float4*)(s + 4);
            } else {        // second half: relu(agg1 + conv1_b)
                const int kb = k0 - 64;
                const float* s = XB + (size_t)nrow * 64 + kb;
                q0 = *(const float4*)s;
                q1 = *(const float4*)(s + 4);
                const float4 c0 = *(const float4*)(CB + kb);
                const float4 c1 = *(const float4*)(CB + kb + 4);
                q0.x = relu(q0.x + c0.x); q0.y = relu(q0.y + c0.y);
                q0.z = relu(q0.z + c0.z); q0.w = relu(q0.w + c0.w);
                q1.x = relu(q1.x + c1.x); q1.y = relu(q1.y + c1.y);
                q1.z = relu(q1.z + c1.z); q1.w = relu(q1.w + c1.w);
            }
        }
        bf16x8 a;
        a[0] = (short)f2bf(q0.x); a[1] = (short)f2bf(q0.y);
        a[2] = (short)f2bf(q0.z); a[3] = (short)f2bf(q0.w);
        a[4] = (short)f2bf(q1.x); a[5] = (short)f2bf(q1.y);
        a[6] = (short)f2bf(q1.z); a[7] = (short)f2bf(q1.w);
#pragma unroll
        for (int c = 0; c < 8; c++) {
            const bf16x8 b = *(const bf16x8*)(Wt + (size_t)((kc * 8 + c) * 64 + lane) * 8);
            acc[c] = __builtin_amdgcn_mfma_f32_16x16x32_bf16(a, b, acc[c], 0, 0, 0);
        }
    }

    const int nb = n0 + quad * 4;
#pragma unroll
    for (int c = 0; c < 4; c++) {
        const int col = c * 16 + lm;
        const float b = B1[col];
#pragma unroll
        for (int r = 0; r < 4; r++) {
            const int n = nb + r;
            if (n < N) O1[(size_t)n * 64 + col] = relu(acc[c][r] + b);
        }
    }
#pragma unroll
    for (int c = 4; c < 8; c++) {
        const int col = (c - 4) * 16 + lm;
#pragma unroll
        for (int r = 0; r < 4; r++) {
            const int n = nb + r;
            if (n < N) O2[(size_t)n * 64 + col] = f2bf(acc[c][r]);
        }
    }
}

// ---- CSR gather-aggregate, bf16 H (128 B rows): half-wave per destination ----
__global__ __launch_bounds__(256) void k_gather64(const int* __restrict__ start,
                                                  const int* __restrict__ degi,
                                                  const int2* __restrict__ rw,
                                                  const unsigned short* __restrict__ H,
                                                  float* __restrict__ AGG, int N) {
    const int l = threadIdx.x & 31;
    const int d = blockIdx.x * 8 + (threadIdx.x >> 5);
    if (d >= N) return;
    int s = start[d];
    const int e2 = s + degi[d];
    float a0 = 0.f, a1 = 0.f;
    for (; s + 1 < e2; s += 2) {
        const int2 ea = rw[s], eb = rw[s + 1];
        const unsigned ua = *(const unsigned*)(H + (size_t)ea.x * 64 + l * 2);
        const unsigned ub = *(const unsigned*)(H + (size_t)eb.x * 64 + l * 2);
        const float wa = __int_as_float(ea.y), wb = __int_as_float(eb.y);
        a0 += wa * __uint_as_float(ua << 16);
        a1 += wa * __uint_as_float(ua & 0xFFFF0000u);
        a0 += wb * __uint_as_float(ub << 16);
        a1 += wb * __uint_as_float(ub & 0xFFFF0000u);
    }
    if (s < e2) {
        const int2 ea = rw[s];
        const unsigned ua = *(const unsigned*)(H + (size_t)ea.x * 64 + l * 2);
        const float wa = __int_as_float(ea.y);
        a0 += wa * __uint_as_float(ua << 16);
        a1 += wa * __uint_as_float(ua & 0xFFFF0000u);
    }
    *(float2*)(AGG + (size_t)d * 64 + l * 2) = make_float2(a0, a1);
}

// ---- combine: x7 = x5 + relu(agg2+cb2); out = x7.fc2w + fc2b + c3b; h3 = x7.c3w ----
__global__ __launch_bounds__(256) void k_combine(const float* __restrict__ X5,
                                                 const float* __restrict__ AGG2,
                                                 const float* __restrict__ CB2,
                                                 const float* __restrict__ FC2W,
                                                 const float* __restrict__ FC2B,
                                                 const float* __restrict__ C3W,
                                                 const float* __restrict__ C3B,
                                                 float* __restrict__ H3,
                                                 float* __restrict__ OUT, int N) {
    const int lane = threadIdx.x & 63;
    const int n = blockIdx.x * 4 + (threadIdx.x >> 6);
    if (n >= N) return;
    const size_t o = (size_t)n * 64 + lane;
    const float v = X5[o] + relu(AGG2[o] + CB2[lane]);
    float p9 = v * FC2W[lane];
    float p10 = v * C3W[lane];
#pragma unroll
    for (int s = 32; s >= 1; s >>= 1) {
        p9 += __shfl_xor(p9, s, 64);
        p10 += __shfl_xor(p10, s, 64);
    }
    if (lane == 0) {
        OUT[n] = p9 + FC2B[0] + C3B[0];
        H3[n] = p10;
    }
}

// ---- final CSR gather, 1 feature ----
__global__ __launch_bounds__(256) void k_gather1f(const int* __restrict__ start,
                                                  const int* __restrict__ degi,
                                                  const int2* __restrict__ rw,
                                                  const float* __restrict__ H3,
                                                  float* __restrict__ OUT, int N) {
    const int d = blockIdx.x * 256 + threadIdx.x;
    if (d >= N) return;
    int s = start[d];
    const int e2 = s + degi[d];
    float acc = 0.f;
    for (; s + 1 < e2; s += 2) {
        const int2 a = rw[s], b = rw[s + 1];
        acc += H3[a.x] * __int_as_float(a.y);
        acc += H3[b.x] * __int_as_float(b.y);
    }
    if (s < e2) {
        const int2 a = rw[s];
        acc += H3[a.x] * __int_as_float(a.y);
    }
    OUT[d] += acc;
}

extern "C" void kernel_launch(void* const* d_in, const int* in_sizes, int n_in,
                              void* d_out, int out_size, void* d_ws, size_t ws_size,
                              hipStream_t stream) {
    const float* x    = (const float*)d_in[0];
    const float* fcw  = (const float*)d_in[1];
    const float* fcb  = (const float*)d_in[2];
    const float* c1w  = (const float*)d_in[3];
    const float* c1b  = (const float*)d_in[4];
    const float* f1w  = (const float*)d_in[5];
    const float* f1b  = (const float*)d_in[6];
    const float* c2w  = (const float*)d_in[7];
    const float* c2b  = (const float*)d_in[8];
    const float* f2w  = (const float*)d_in[9];
    const float* f2b  = (const float*)d_in[10];
    const float* c3w  = (const float*)d_in[11];
    const float* c3b  = (const float*)d_in[12];
    const int*   ei   = (const int*)d_in[13];

    const int N = in_sizes[0] / IN_DIM;
    const int E = in_sizes[13] / 2;
    const int* row = ei;
    const int* col = ei + E;
    float* out = (float*)d_out;

    const int NR = (N + RB - 1) >> RB_SHIFT;

    const size_t Npad = ((size_t)N + 127) & ~(size_t)127;
    const size_t Epad = ((size_t)E + 127) & ~(size_t)127;
    const size_t NF = (size_t)N * 64;
    int*   binCur = (int*)d_ws;                          // NBMAX
    int*   degi   = binCur + NBMAX;                      // N
    float* dinv   = (float*)(degi + Npad);               // N
    int*   start  = (int*)(dinv + Npad);                 // N
    int*   bsum   = start + Npad;                        // 512
    unsigned short* Wt = (unsigned short*)(bsum + 512);  // 2*16384 bf16 (64 KB)
    int2*  part   = (int2*)(Wt + 2 * 16384);             // NR*MAXBIN
    int2*  rw     = part + (size_t)NR * MAXBIN;          // E
    float* x1     = (float*)(rw + Epad);                 // N*64 f32
    unsigned short* h1 = (unsigned short*)(x1 + NF);     // N*64 bf16
    float* agg1   = (float*)(h1 + NF);                   // N*64 f32
    float* x5     = agg1 + NF;                           // N*64 f32
    unsigned short* h2 = h1;   // h1 dead after gather1
    float* agg2   = x1;        // x1 dead after gemm2
    float* h3     = agg1;      // agg1 dead after gemm2

    const int gN = (N + 255) / 256;
    const int NB = (N + 255) / 256;
    const int gG = (N + 63) / 64;
    const int gW = (N + 7) / 8;
    const int gC = (N + 3) / 4;
    const int gP = (E + PCH - 1) / PCH;

    // --- CSR build + weight repack ---
    k_initbins<<<1, NBMAX, 0, stream>>>(binCur, NR);
    k_wprep<<<16, 256, 0, stream>>>(fcw, c1w, f1w, c2w, Wt);
    k_part<<<gP, 256, 0, stream>>>(row, col, binCur, part, E);
    k_hist<<<NR, 256, 0, stream>>>(binCur, part, degi, dinv, N);
    k_scan1<<<NB, 256, 0, stream>>>(degi, start, bsum, N);
    k_scan2<<<1, 512, 0, stream>>>(bsum, NB);
    k_scan3<<<NB, 256, 0, stream>>>(start, bsum, N);
    k_bucket3<<<NR, 256, 0, stream>>>(binCur, part, start, dinv, rw, N);

    // --- layer 1 ---
    k_gemm<1><<<gG, 256, 0, stream>>>(x, nullptr, nullptr, Wt, fcb, x1, h1, N);
    k_gather64<<<gW, 256, 0, stream>>>(start, degi, rw, h1, agg1, N);

    // --- layer 2 ---
    k_gemm<2><<<gG, 256, 0, stream>>>(x1, agg1, c1b, Wt + 16384, f1b, x5, h2, N);
    k_gather64<<<gW, 256, 0, stream>>>(start, degi, rw, h2, agg2, N);

    // --- layer 3 ---
    k_combine<<<gC, 256, 0, stream>>>(x5, agg2, c2b, f2w, f2b, c3w, c3b, h3, out, N);
    k_gather1f<<<gN, 256, 0, stream>>>(start, degi, rw, h3, out, N);
}

// Round 9
// 310.569 us; speedup vs baseline: 1.6389x; 1.1047x over previous
//
#include <hip/hip_runtime.h>

#define IN_DIM 128
#define HID 64
#define RB_SHIFT 10 // 1024 nodes per dest-range
#define RB 1024
#define NBMAX 128   // max ranges (N <= 128K)
#define MAXBIN 16384 // capacity per range bin region (mean ~12.3K)
#define PCH 2048    // edges per k_part block

typedef short bf16x8 __attribute__((ext_vector_type(8)));
typedef float f32x4  __attribute__((ext_vector_type(4)));

__device__ __forceinline__ float relu(float v) { return v > 0.f ? v : 0.f; }

// fp32 -> bf16 with round-to-nearest-even
__device__ __forceinline__ unsigned short f2bf(float f) {
    unsigned u = __float_as_uint(f);
    u += 0x7FFFu + ((u >> 16) & 1u);
    return (unsigned short)(u >> 16);
}

__device__ __forceinline__ float bflo(unsigned u) { return __uint_as_float(u << 16); }
__device__ __forceinline__ float bfhi(unsigned u) { return __uint_as_float(u & 0xFFFF0000u); }

// ---- init bin cursors to fixed region bases ----
__global__ void k_initbins(int* __restrict__ binCursor, int NR) {
    if (threadIdx.x < NR) binCursor[threadIdx.x] = threadIdx.x * MAXBIN;
}

// ---- one-time weight repack into MFMA B-fragment order ----
// Wt[layer][kc][c][lane][j] bf16 : B[k=kc*32+(lane>>4)*8+j][col=c*16+(lane&15)]
__global__ __launch_bounds__(256) void k_wprep(const float* __restrict__ W1a,
                                               const float* __restrict__ W2a,
                                               const float* __restrict__ W1b,
                                               const float* __restrict__ W2b,
                                               unsigned short* __restrict__ Wt) {
    const int t = blockIdx.x * 256 + threadIdx.x;   // (layer,kc,c,lane)
    if (t >= 2 * 4 * 8 * 64) return;
    const int lane = t & 63;
    const int c = (t >> 6) & 7;
    const int kc = (t >> 9) & 3;
    const int layer = t >> 11;
    const int col = c * 16 + (lane & 15);
    const int k0 = kc * 32 + (lane >> 4) * 8;
    const float* W1 = layer ? W1b : W1a;
    const float* W2 = layer ? W2b : W2a;
    const float* src = (col < 64) ? (W1 + col) : (W2 + (col - 64));
    unsigned short v[8];
#pragma unroll
    for (int j = 0; j < 8; j++) v[j] = f2bf(src[(size_t)(k0 + j) * 64]);
    *(ushort4*)(Wt + (size_t)t * 8) = make_ushort4(v[0], v[1], v[2], v[3]);
    *(ushort4*)(Wt + (size_t)t * 8 + 4) = make_ushort4(v[4], v[5], v[6], v[7]);
}

// ---- phase 1: partition edges into dest-ranges ----
__global__ __launch_bounds__(256) void k_part(const int* __restrict__ row,
                                              const int* __restrict__ col,
                                              int* __restrict__ binCursor,
                                              int2* __restrict__ part, int E) {
    __shared__ int lcur[NBMAX], gbase[NBMAX];
    const int tid = threadIdx.x;
    const int e0 = blockIdx.x * PCH;
    const int cnt = min(PCH, E - e0);
    if (tid < NBMAX) lcur[tid] = 0;
    __syncthreads();
    int rr[8], cc[8], pp[8];
    if (cnt == PCH) {
#pragma unroll
        for (int h = 0; h < 2; h++) {
            const int4 c4 = *(const int4*)(col + e0 + h * 1024 + tid * 4);
            const int4 r4 = *(const int4*)(row + e0 + h * 1024 + tid * 4);
            cc[h * 4 + 0] = c4.x; cc[h * 4 + 1] = c4.y;
            cc[h * 4 + 2] = c4.z; cc[h * 4 + 3] = c4.w;
            rr[h * 4 + 0] = r4.x; rr[h * 4 + 1] = r4.y;
            rr[h * 4 + 2] = r4.z; rr[h * 4 + 3] = r4.w;
        }
    } else {
#pragma unroll
        for (int j = 0; j < 8; j++) {
            const int e = e0 + j * 256 + tid;
            if (e < e0 + cnt) { rr[j] = row[e]; cc[j] = col[e]; }
            else cc[j] = -1;
        }
    }
#pragma unroll
    for (int j = 0; j < 8; j++)
        if (cc[j] >= 0) pp[j] = atomicAdd(&lcur[cc[j] >> RB_SHIFT], 1);
    __syncthreads();
    if (tid < NBMAX && lcur[tid] > 0)
        gbase[tid] = atomicAdd(&binCursor[tid], lcur[tid]);
    __syncthreads();
#pragma unroll
    for (int j = 0; j < 8; j++)
        if (cc[j] >= 0)
            part[gbase[cc[j] >> RB_SHIFT] + pp[j]] = make_int2(rr[j], cc[j]);
}

// ---- phase 2: per-range private histogram -> degi, dinv ----
__global__ __launch_bounds__(256) void k_hist(const int* __restrict__ binCursor,
                                              const int2* __restrict__ part,
                                              int* __restrict__ degi,
                                              float* __restrict__ dinv, int N) {
    __shared__ int cnt[RB];
    const int b = blockIdx.x;
    const int lo = b << RB_SHIFT;
    const int tid = threadIdx.x;
    for (int i = tid; i < RB; i += 256) cnt[i] = 0;
    __syncthreads();
    const int base = b * MAXBIN;
    const int tot = binCursor[b] - base;
    for (int i = tid; i < tot; i += 256)
        atomicAdd(&cnt[part[base + i].y - lo], 1);
    __syncthreads();
    for (int i = tid; i < RB; i += 256) {
        const int n = lo + i;
        if (n < N) {
            const int d = cnt[i];
            degi[n] = d;
            dinv[n] = d > 0 ? rsqrtf((float)d) : 0.f;
        }
    }
}

// ---- scan pass 1 ----
__global__ __launch_bounds__(256) void k_scan1(const int* __restrict__ degi,
                                               int* __restrict__ start,
                                               int* __restrict__ bsum, int N) {
    __shared__ int s[256];
    const int tid = threadIdx.x;
    const int i = blockIdx.x * 256 + tid;
    const int v = (i < N) ? degi[i] : 0;
    s[tid] = v;
    __syncthreads();
    for (int off = 1; off < 256; off <<= 1) {
        int t = (tid >= off) ? s[tid - off] : 0;
        __syncthreads();
        s[tid] += t;
        __syncthreads();
    }
    if (i < N) start[i] = s[tid] - v;
    if (tid == 255) bsum[blockIdx.x] = s[255];
}

// ---- scan pass 2 ----
__global__ __launch_bounds__(512) void k_scan2(int* __restrict__ bsum, int NB) {
    __shared__ int s[512];
    const int tid = threadIdx.x;
    const int v = (tid < NB) ? bsum[tid] : 0;
    s[tid] = v;
    __syncthreads();
    for (int off = 1; off < 512; off <<= 1) {
        int t = (tid >= off) ? s[tid - off] : 0;
        __syncthreads();
        s[tid] += t;
        __syncthreads();
    }
    if (tid < NB) bsum[tid] = s[tid] - v;
}

// ---- scan pass 3 ----
__global__ __launch_bounds__(256) void k_scan3(int* __restrict__ start,
                                               const int* __restrict__ bsum, int N) {
    int i = blockIdx.x * 256 + threadIdx.x;
    if (i < N) start[i] += bsum[blockIdx.x];
}

// ---- phase 3: per-range bucket with LDS cursors ----
__global__ __launch_bounds__(256) void k_bucket3(const int* __restrict__ binCursor,
                                                 const int2* __restrict__ part,
                                                 const int* __restrict__ start,
                                                 const float* __restrict__ dinv,
                                                 int2* __restrict__ rw, int N) {
    __shared__ int curs[RB];
    __shared__ float dv[RB];
    const int b = blockIdx.x;
    const int lo = b << RB_SHIFT;
    const int tid = threadIdx.x;
    for (int i = tid; i < RB; i += 256) {
        const int n = lo + i;
        curs[i] = (n < N) ? start[n] : 0;
        dv[i] = (n < N) ? dinv[n] : 0.f;
    }
    __syncthreads();
    const int base = b * MAXBIN;
    const int tot = binCursor[b] - base;
    for (int i = tid; i < tot; i += 256) {
        const int2 v = part[base + i];
        const int li = v.y - lo;
        const int pos = atomicAdd(&curs[li], 1);
        rw[pos] = make_int2(v.x, __float_as_int(dinv[v.x] * dv[li]));
    }
}

// ---- MFMA dual GEMM: O1 = relu(Xcat @ W1 + B1) fp32, O2 = Xcat @ W2 bf16 ----
template <int LAYER>
__global__ __launch_bounds__(256) void k_gemm(const float* __restrict__ XA,
                                              const float* __restrict__ XB,
                                              const float* __restrict__ CB,
                                              const unsigned short* __restrict__ Wt,
                                              const float* __restrict__ B1,
                                              float* __restrict__ O1,
                                              unsigned short* __restrict__ O2,
                                              int N) {
    const int tid = threadIdx.x;
    const int wave = tid >> 6;
    const int lane = tid & 63;
    const int quad = lane >> 4;
    const int lm = lane & 15;
    const int n0 = blockIdx.x * 64 + wave * 16;
    if (n0 >= N) return;
    const int nrow = min(n0 + lm, N - 1);

    f32x4 acc[8];
#pragma unroll
    for (int c = 0; c < 8; c++) acc[c] = (f32x4){0.f, 0.f, 0.f, 0.f};

#pragma unroll
    for (int kc = 0; kc < 4; kc++) {
        const int k0 = kc * 32 + quad * 8;
        float4 q0, q1;
        if (LAYER == 1) {
            const float* s = XA + (size_t)nrow * IN_DIM + k0;
            q0 = *(const float4*)s;
            q1 = *(const float4*)(s + 4);
        } else {
            if (kc < 2) {
                const float* s = XA + (size_t)nrow * 64 + k0;
                q0 = *(const float4*)s;
                q1 = *(const float4*)(s + 4);
            } else {
                const int kb = k0 - 64;
                const float* s = XB + (size_t)nrow * 64 + kb;
                q0 = *(const float4*)s;
                q1 = *(const float4*)(s + 4);
                const float4 c0 = *(const float4*)(CB + kb);
                const float4 c1 = *(const float4*)(CB + kb + 4);
                q0.x = relu(q0.x + c0.x); q0.y = relu(q0.y + c0.y);
                q0.z = relu(q0.z + c0.z); q0.w = relu(q0.w + c0.w);
                q1.x = relu(q1.x + c1.x); q1.y = relu(q1.y + c1.y);
                q1.z = relu(q1.z + c1.z); q1.w = relu(q1.w + c1.w);
            }
        }
        bf16x8 a;
        a[0] = (short)f2bf(q0.x); a[1] = (short)f2bf(q0.y);
        a[2] = (short)f2bf(q0.z); a[3] = (short)f2bf(q0.w);
        a[4] = (short)f2bf(q1.x); a[5] = (short)f2bf(q1.y);
        a[6] = (short)f2bf(q1.z); a[7] = (short)f2bf(q1.w);
#pragma unroll
        for (int c = 0; c < 8; c++) {
            const bf16x8 b = *(const bf16x8*)(Wt + (size_t)((kc * 8 + c) * 64 + lane) * 8);
            acc[c] = __builtin_amdgcn_mfma_f32_16x16x32_bf16(a, b, acc[c], 0, 0, 0);
        }
    }

    const int nb = n0 + quad * 4;
#pragma unroll
    for (int c = 0; c < 4; c++) {
        const int col = c * 16 + lm;
        const float b = B1[col];
#pragma unroll
        for (int r = 0; r < 4; r++) {
            const int n = nb + r;
            if (n < N) O1[(size_t)n * 64 + col] = relu(acc[c][r] + b);
        }
    }
#pragma unroll
    for (int c = 4; c < 8; c++) {
        const int col = (c - 4) * 16 + lm;
#pragma unroll
        for (int r = 0; r < 4; r++) {
            const int n = nb + r;
            if (n < N) O2[(size_t)n * 64 + col] = f2bf(acc[c][r]);
        }
    }
}

// ---- CSR gather-aggregate, bf16 H (128 B rows) ----
// quarter-wave (16 lanes) per destination, 4 feats/lane (8 B load/lane),
// edge loop unrolled x4 -> 16 independent H-row loads in flight per wave
// (round-8: half-wave/unroll-2 was latency-bound at 1.95 TB/s, 28% VALU).
__global__ __launch_bounds__(256) void k_gather64(const int* __restrict__ start,
                                                  const int* __restrict__ degi,
                                                  const int2* __restrict__ rw,
                                                  const unsigned short* __restrict__ H,
                                                  float* __restrict__ AGG, int N) {
    const int l = threadIdx.x & 15;               // feats 4l..4l+3
    const int d = blockIdx.x * 16 + (threadIdx.x >> 4);
    if (d >= N) return;
    int s = start[d];
    const int e2 = s + degi[d];
    float a0 = 0.f, a1 = 0.f, a2 = 0.f, a3 = 0.f;
    for (; s + 3 < e2; s += 4) {
        const int2 ea = rw[s], eb = rw[s + 1], ec = rw[s + 2], ed = rw[s + 3];
        const uint2 ua = *(const uint2*)(H + (size_t)ea.x * 64 + l * 4);
        const uint2 ub = *(const uint2*)(H + (size_t)eb.x * 64 + l * 4);
        const uint2 uc = *(const uint2*)(H + (size_t)ec.x * 64 + l * 4);
        const uint2 ud = *(const uint2*)(H + (size_t)ed.x * 64 + l * 4);
        const float wa = __int_as_float(ea.y), wb = __int_as_float(eb.y);
        const float wc = __int_as_float(ec.y), wd = __int_as_float(ed.y);
        a0 += wa * bflo(ua.x); a1 += wa * bfhi(ua.x);
        a2 += wa * bflo(ua.y); a3 += wa * bfhi(ua.y);
        a0 += wb * bflo(ub.x); a1 += wb * bfhi(ub.x);
        a2 += wb * bflo(ub.y); a3 += wb * bfhi(ub.y);
        a0 += wc * bflo(uc.x); a1 += wc * bfhi(uc.x);
        a2 += wc * bflo(uc.y); a3 += wc * bfhi(uc.y);
        a0 += wd * bflo(ud.x); a1 += wd * bfhi(ud.x);
        a2 += wd * bflo(ud.y); a3 += wd * bfhi(ud.y);
    }
    for (; s < e2; ++s) {
        const int2 ea = rw[s];
        const uint2 ua = *(const uint2*)(H + (size_t)ea.x * 64 + l * 4);
        const float wa = __int_as_float(ea.y);
        a0 += wa * bflo(ua.x); a1 += wa * bfhi(ua.x);
        a2 += wa * bflo(ua.y); a3 += wa * bfhi(ua.y);
    }
    *(float4*)(AGG + (size_t)d * 64 + l * 4) = make_float4(a0, a1, a2, a3);
}

// ---- combine: x7 = x5 + relu(agg2+cb2); out = x7.fc2w + fc2b + c3b; h3 = x7.c3w ----
__global__ __launch_bounds__(256) void k_combine(const float* __restrict__ X5,
                                                 const float* __restrict__ AGG2,
                                                 const float* __restrict__ CB2,
                                                 const float* __restrict__ FC2W,
                                                 const float* __restrict__ FC2B,
                                                 const float* __restrict__ C3W,
                                                 const float* __restrict__ C3B,
                                                 float* __restrict__ H3,
                                                 float* __restrict__ OUT, int N) {
    const int lane = threadIdx.x & 63;
    const int n = blockIdx.x * 4 + (threadIdx.x >> 6);
    if (n >= N) return;
    const size_t o = (size_t)n * 64 + lane;
    const float v = X5[o] + relu(AGG2[o] + CB2[lane]);
    float p9 = v * FC2W[lane];
    float p10 = v * C3W[lane];
#pragma unroll
    for (int s = 32; s >= 1; s >>= 1) {
        p9 += __shfl_xor(p9, s, 64);
        p10 += __shfl_xor(p10, s, 64);
    }
    if (lane == 0) {
        OUT[n] = p9 + FC2B[0] + C3B[0];
        H3[n] = p10;
    }
}

// ---- final CSR gather, 1 feature ----
__global__ __launch_bounds__(256) void k_gather1f(const int* __restrict__ start,
                                                  const int* __restrict__ degi,
                                                  const int2* __restrict__ rw,
                                                  const float* __restrict__ H3,
                                                  float* __restrict__ OUT, int N) {
    const int d = blockIdx.x * 256 + threadIdx.x;
    if (d >= N) return;
    int s = start[d];
    const int e2 = s + degi[d];
    float acc = 0.f;
    for (; s + 1 < e2; s += 2) {
        const int2 a = rw[s], b = rw[s + 1];
        acc += H3[a.x] * __int_as_float(a.y);
        acc += H3[b.x] * __int_as_float(b.y);
    }
    if (s < e2) {
        const int2 a = rw[s];
        acc += H3[a.x] * __int_as_float(a.y);
    }
    OUT[d] += acc;
}

extern "C" void kernel_launch(void* const* d_in, const int* in_sizes, int n_in,
                              void* d_out, int out_size, void* d_ws, size_t ws_size,
                              hipStream_t stream) {
    const float* x    = (const float*)d_in[0];
    const float* fcw  = (const float*)d_in[1];
    const float* fcb  = (const float*)d_in[2];
    const float* c1w  = (const float*)d_in[3];
    const float* c1b  = (const float*)d_in[4];
    const float* f1w  = (const float*)d_in[5];
    const float* f1b  = (const float*)d_in[6];
    const float* c2w  = (const float*)d_in[7];
    const float* c2b  = (const float*)d_in[8];
    const float* f2w  = (const float*)d_in[9];
    const float* f2b  = (const float*)d_in[10];
    const float* c3w  = (const float*)d_in[11];
    const float* c3b  = (const float*)d_in[12];
    const int*   ei   = (const int*)d_in[13];

    const int N = in_sizes[0] / IN_DIM;
    const int E = in_sizes[13] / 2;
    const int* row = ei;
    const int* col = ei + E;
    float* out = (float*)d_out;

    const int NR = (N + RB - 1) >> RB_SHIFT;

    const size_t Npad = ((size_t)N + 127) & ~(size_t)127;
    const size_t Epad = ((size_t)E + 127) & ~(size_t)127;
    const size_t NF = (size_t)N * 64;
    int*   binCur = (int*)d_ws;                          // NBMAX
    int*   degi   = binCur + NBMAX;                      // N
    float* dinv   = (float*)(degi + Npad);               // N
    int*   start  = (int*)(dinv + Npad);                 // N
    int*   bsum   = start + Npad;                        // 512
    unsigned short* Wt = (unsigned short*)(bsum + 512);  // 2*16384 bf16
    int2*  part   = (int2*)(Wt + 2 * 16384);             // NR*MAXBIN
    int2*  rw     = part + (size_t)NR * MAXBIN;          // E
    float* x1     = (float*)(rw + Epad);                 // N*64 f32
    unsigned short* h1 = (unsigned short*)(x1 + NF);     // N*64 bf16
    float* agg1   = (float*)(h1 + NF);                   // N*64 f32
    float* x5     = agg1 + NF;                           // N*64 f32
    unsigned short* h2 = h1;   // h1 dead after gather1
    float* agg2   = x1;        // x1 dead after gemm2
    float* h3     = agg1;      // agg1 dead after gemm2

    const int gN = (N + 255) / 256;
    const int NB = (N + 255) / 256;
    const int gG = (N + 63) / 64;
    const int gW = (N + 15) / 16;
    const int gC = (N + 3) / 4;
    const int gP = (E + PCH - 1) / PCH;

    // --- CSR build + weight repack ---
    k_initbins<<<1, NBMAX, 0, stream>>>(binCur, NR);
    k_wprep<<<16, 256, 0, stream>>>(fcw, c1w, f1w, c2w, Wt);
    k_part<<<gP, 256, 0, stream>>>(row, col, binCur, part, E);
    k_hist<<<NR, 256, 0, stream>>>(binCur, part, degi, dinv, N);
    k_scan1<<<NB, 256, 0, stream>>>(degi, start, bsum, N);
    k_scan2<<<1, 512, 0, stream>>>(bsum, NB);
    k_scan3<<<NB, 256, 0, stream>>>(start, bsum, N);
    k_bucket3<<<NR, 256, 0, stream>>>(binCur, part, start, dinv, rw, N);

    // --- layer 1 ---
    k_gemm<1><<<gG, 256, 0, stream>>>(x, nullptr, nullptr, Wt, fcb, x1, h1, N);
    k_gather64<<<gW, 256, 0, stream>>>(start, degi, rw, h1, agg1, N);

    // --- layer 2 ---
    k_gemm<2><<<gG, 256, 0, stream>>>(x1, agg1, c1b, Wt + 16384, f1b, x5, h2, N);
    k_gather64<<<gW, 256, 0, stream>>>(start, degi, rw, h2, agg2, N);

    // --- layer 3 ---
    k_combine<<<gC, 256, 0, stream>>>(x5, agg2, c2b, f2w, f2b, c3w, c3b, h3, out, N);
    k_gather1f<<<gN, 256, 0, stream>>>(start, degi, rw, h3, out, N);
}

// Round 10
// 285.526 us; speedup vs baseline: 1.7826x; 1.0877x over previous
//
#include <hip/hip_runtime.h>

#define IN_DIM 128
#define HID 64
#define RB_SHIFT 10 // 1024 nodes per dest-range
#define RB 1024
#define NBMAX 128   // max ranges (N <= 128K)
#define MAXBIN 16384 // capacity per range bin region (mean ~12.3K)
#define PCH 2048    // edges per k_part block

typedef short bf16x8 __attribute__((ext_vector_type(8)));
typedef float f32x4  __attribute__((ext_vector_type(4)));

__device__ __forceinline__ float relu(float v) { return v > 0.f ? v : 0.f; }

// fp32 -> bf16 round-to-nearest-even
__device__ __forceinline__ unsigned short f2bf(float f) {
    unsigned u = __float_as_uint(f);
    u += 0x7FFFu + ((u >> 16) & 1u);
    return (unsigned short)(u >> 16);
}
__device__ __forceinline__ float bflo(unsigned u) { return __uint_as_float(u << 16); }
__device__ __forceinline__ float bfhi(unsigned u) { return __uint_as_float(u & 0xFFFF0000u); }

// ---- weight repack into MFMA B-frag order (+ binCursor init, block 0) ----
// Wt[layer][kc][c][lane][j] bf16 : B[k=kc*32+(lane>>4)*8+j][col=c*16+(lane&15)]
__global__ __launch_bounds__(256) void k_wprep(const float* __restrict__ W1a,
                                               const float* __restrict__ W2a,
                                               const float* __restrict__ W1b,
                                               const float* __restrict__ W2b,
                                               unsigned short* __restrict__ Wt,
                                               int* __restrict__ binCursor, int NR) {
    if (blockIdx.x == 0 && threadIdx.x < NR) binCursor[threadIdx.x] = threadIdx.x * MAXBIN;
    const int t = blockIdx.x * 256 + threadIdx.x;   // (layer,kc,c,lane)
    if (t >= 2 * 4 * 8 * 64) return;
    const int lane = t & 63;
    const int c = (t >> 6) & 7;
    const int kc = (t >> 9) & 3;
    const int layer = t >> 11;
    const int col = c * 16 + (lane & 15);
    const int k0 = kc * 32 + (lane >> 4) * 8;
    const float* W1 = layer ? W1b : W1a;
    const float* W2 = layer ? W2b : W2a;
    const float* src = (col < 64) ? (W1 + col) : (W2 + (col - 64));
    unsigned short v[8];
#pragma unroll
    for (int j = 0; j < 8; j++) v[j] = f2bf(src[(size_t)(k0 + j) * 64]);
    *(ushort4*)(Wt + (size_t)t * 8) = make_ushort4(v[0], v[1], v[2], v[3]);
    *(ushort4*)(Wt + (size_t)t * 8 + 4) = make_ushort4(v[4], v[5], v[6], v[7]);
}

// ---- phase 1: partition edges into dest-ranges ----
__global__ __launch_bounds__(256) void k_part(const int* __restrict__ row,
                                              const int* __restrict__ col,
                                              int* __restrict__ binCursor,
                                              int2* __restrict__ part, int E) {
    __shared__ int lcur[NBMAX], gbase[NBMAX];
    const int tid = threadIdx.x;
    const int e0 = blockIdx.x * PCH;
    const int cnt = min(PCH, E - e0);
    if (tid < NBMAX) lcur[tid] = 0;
    __syncthreads();
    int rr[8], cc[8], pp[8];
    if (cnt == PCH) {
#pragma unroll
        for (int h = 0; h < 2; h++) {
            const int4 c4 = *(const int4*)(col + e0 + h * 1024 + tid * 4);
            const int4 r4 = *(const int4*)(row + e0 + h * 1024 + tid * 4);
            cc[h * 4 + 0] = c4.x; cc[h * 4 + 1] = c4.y;
            cc[h * 4 + 2] = c4.z; cc[h * 4 + 3] = c4.w;
            rr[h * 4 + 0] = r4.x; rr[h * 4 + 1] = r4.y;
            rr[h * 4 + 2] = r4.z; rr[h * 4 + 3] = r4.w;
        }
    } else {
#pragma unroll
        for (int j = 0; j < 8; j++) {
            const int e = e0 + j * 256 + tid;
            if (e < e0 + cnt) { rr[j] = row[e]; cc[j] = col[e]; }
            else cc[j] = -1;
        }
    }
#pragma unroll
    for (int j = 0; j < 8; j++)
        if (cc[j] >= 0) pp[j] = atomicAdd(&lcur[cc[j] >> RB_SHIFT], 1);
    __syncthreads();
    if (tid < NBMAX && lcur[tid] > 0)
        gbase[tid] = atomicAdd(&binCursor[tid], lcur[tid]);
    __syncthreads();
#pragma unroll
    for (int j = 0; j < 8; j++)
        if (cc[j] >= 0)
            part[gbase[cc[j] >> RB_SHIFT] + pp[j]] = make_int2(rr[j], cc[j]);
}

// ---- phase 2: per-range histogram + local 1024-scan -> degi, dinv, start ----
// start is region-local (base = b*MAXBIN): no global scan needed.
__global__ __launch_bounds__(256) void k_csrA(const int* __restrict__ binCursor,
                                              const int2* __restrict__ part,
                                              int* __restrict__ degi,
                                              float* __restrict__ dinv,
                                              int* __restrict__ start, int N) {
    __shared__ int cnt[RB];
    __shared__ int psum[256];
    const int b = blockIdx.x;
    const int lo = b << RB_SHIFT;
    const int tid = threadIdx.x;
    for (int i = tid; i < RB; i += 256) cnt[i] = 0;
    __syncthreads();
    const int base = b * MAXBIN;
    const int tot = binCursor[b] - base;
    for (int i = tid; i < tot; i += 256)
        atomicAdd(&cnt[part[base + i].y - lo], 1);
    __syncthreads();
    const int i0 = tid * 4;
    const int c0 = cnt[i0], c1 = cnt[i0 + 1], c2 = cnt[i0 + 2], c3 = cnt[i0 + 3];
    const int s = c0 + c1 + c2 + c3;
    psum[tid] = s;
    __syncthreads();
    for (int off = 1; off < 256; off <<= 1) {
        int t = (tid >= off) ? psum[tid - off] : 0;
        __syncthreads();
        psum[tid] += t;
        __syncthreads();
    }
    const int e = psum[tid] - s;   // exclusive
    const int offs[4] = {e, e + c0, e + c0 + c1, e + c0 + c1 + c2};
    const int cs[4] = {c0, c1, c2, c3};
#pragma unroll
    for (int j = 0; j < 4; j++) {
        const int n = lo + i0 + j;
        if (n < N) {
            degi[n] = cs[j];
            start[n] = base + offs[j];
            dinv[n] = cs[j] > 0 ? rsqrtf((float)cs[j]) : 0.f;
        }
    }
}

// ---- phase 3: per-range bucket with LDS cursors (dinv now globally complete) ----
__global__ __launch_bounds__(256) void k_csrB(const int* __restrict__ binCursor,
                                              const int2* __restrict__ part,
                                              const int* __restrict__ start,
                                              const float* __restrict__ dinv,
                                              int2* __restrict__ rw, int N) {
    __shared__ int curs[RB];
    __shared__ float dv[RB];
    const int b = blockIdx.x;
    const int lo = b << RB_SHIFT;
    const int tid = threadIdx.x;
    for (int i = tid; i < RB; i += 256) {
        const int n = lo + i;
        curs[i] = (n < N) ? start[n] : 0;
        dv[i] = (n < N) ? dinv[n] : 0.f;
    }
    __syncthreads();
    const int base = b * MAXBIN;
    const int tot = binCursor[b] - base;
    for (int i = tid; i < tot; i += 256) {
        const int2 v = part[base + i];
        const int li = v.y - lo;
        const int pos = atomicAdd(&curs[li], 1);
        rw[pos] = make_int2(v.x, __float_as_int(dinv[v.x] * dv[li]));
    }
}

// ---- MFMA dual GEMM ----
// LAYER 1: A = X fp32 (cvt bf16); O1 = x1 bf16 (relu+bias), O2 = h1 bf16.
// LAYER 2: A = [x1bf | x2bf] direct bf16 loads; O1 = x5 fp32, O2 = h2 bf16.
template <int LAYER>
__global__ __launch_bounds__(256) void k_gemm(const float* __restrict__ XF,
                                              const unsigned short* __restrict__ X1B,
                                              const unsigned short* __restrict__ X2B,
                                              const unsigned short* __restrict__ Wt,
                                              const float* __restrict__ B1,
                                              float* __restrict__ O1f,
                                              unsigned short* __restrict__ O1b,
                                              unsigned short* __restrict__ O2,
                                              int N) {
    const int tid = threadIdx.x;
    const int wave = tid >> 6;
    const int lane = tid & 63;
    const int quad = lane >> 4;
    const int lm = lane & 15;
    const int n0 = blockIdx.x * 64 + wave * 16;
    if (n0 >= N) return;
    const int nrow = min(n0 + lm, N - 1);

    f32x4 acc[8];
#pragma unroll
    for (int c = 0; c < 8; c++) acc[c] = (f32x4){0.f, 0.f, 0.f, 0.f};

#pragma unroll
    for (int kc = 0; kc < 4; kc++) {
        const int k0 = kc * 32 + quad * 8;
        bf16x8 a;
        if (LAYER == 1) {
            const float* s = XF + (size_t)nrow * IN_DIM + k0;
            const float4 q0 = *(const float4*)s;
            const float4 q1 = *(const float4*)(s + 4);
            a[0] = (short)f2bf(q0.x); a[1] = (short)f2bf(q0.y);
            a[2] = (short)f2bf(q0.z); a[3] = (short)f2bf(q0.w);
            a[4] = (short)f2bf(q1.x); a[5] = (short)f2bf(q1.y);
            a[6] = (short)f2bf(q1.z); a[7] = (short)f2bf(q1.w);
        } else {
            const unsigned short* s = (kc < 2) ? (X1B + (size_t)nrow * 64 + k0)
                                               : (X2B + (size_t)nrow * 64 + (k0 - 64));
            a = *(const bf16x8*)s;
        }
#pragma unroll
        for (int c = 0; c < 8; c++) {
            const bf16x8 b = *(const bf16x8*)(Wt + (size_t)((kc * 8 + c) * 64 + lane) * 8);
            acc[c] = __builtin_amdgcn_mfma_f32_16x16x32_bf16(a, b, acc[c], 0, 0, 0);
        }
    }

    const int nb = n0 + quad * 4;
#pragma unroll
    for (int c = 0; c < 4; c++) {
        const int col = c * 16 + lm;
        const float b = B1[col];
#pragma unroll
        for (int r = 0; r < 4; r++) {
            const int n = nb + r;
            if (n < N) {
                const float v = relu(acc[c][r] + b);
                if (LAYER == 1) O1b[(size_t)n * 64 + col] = f2bf(v);
                else            O1f[(size_t)n * 64 + col] = v;
            }
        }
    }
#pragma unroll
    for (int c = 4; c < 8; c++) {
        const int col = (c - 4) * 16 + lm;
#pragma unroll
        for (int r = 0; r < 4; r++) {
            const int n = nb + r;
            if (n < N) O2[(size_t)n * 64 + col] = f2bf(acc[c][r]);
        }
    }
}

// ---- CSR gather, bf16 H, quarter-wave/dest, 4 feats/lane, unroll 4 ----
// MODE 1: epilogue stores x2 = relu(agg + CB) as bf16 (feeds gemm2 directly).
// MODE 2: fused combine: v = x5 + relu(agg + CB); 16-lane dot with fc2w/c3w;
//         writes out[d] and h3[d]. agg never materialized.
template <int MODE>
__global__ __launch_bounds__(256) void k_gather(const int* __restrict__ start,
                                                const int* __restrict__ degi,
                                                const int2* __restrict__ rw,
                                                const unsigned short* __restrict__ H,
                                                const float* __restrict__ CB,
                                                unsigned short* __restrict__ OXB,
                                                const float* __restrict__ X5,
                                                const float* __restrict__ FC2W,
                                                const float* __restrict__ FC2B,
                                                const float* __restrict__ C3W,
                                                const float* __restrict__ C3B,
                                                float* __restrict__ H3,
                                                float* __restrict__ OUT, int N) {
    const int l = threadIdx.x & 15;               // feats 4l..4l+3
    const int d = blockIdx.x * 16 + (threadIdx.x >> 4);
    if (d >= N) return;
    int s = start[d];
    const int e2 = s + degi[d];
    float a0 = 0.f, a1 = 0.f, a2 = 0.f, a3 = 0.f;
    for (; s + 3 < e2; s += 4) {
        const int2 ea = rw[s], eb = rw[s + 1], ec = rw[s + 2], ed = rw[s + 3];
        const uint2 ua = *(const uint2*)(H + (size_t)ea.x * 64 + l * 4);
        const uint2 ub = *(const uint2*)(H + (size_t)eb.x * 64 + l * 4);
        const uint2 uc = *(const uint2*)(H + (size_t)ec.x * 64 + l * 4);
        const uint2 ud = *(const uint2*)(H + (size_t)ed.x * 64 + l * 4);
        const float wa = __int_as_float(ea.y), wb = __int_as_float(eb.y);
        const float wc = __int_as_float(ec.y), wd = __int_as_float(ed.y);
        a0 += wa * bflo(ua.x); a1 += wa * bfhi(ua.x);
        a2 += wa * bflo(ua.y); a3 += wa * bfhi(ua.y);
        a0 += wb * bflo(ub.x); a1 += wb * bfhi(ub.x);
        a2 += wb * bflo(ub.y); a3 += wb * bfhi(ub.y);
        a0 += wc * bflo(uc.x); a1 += wc * bfhi(uc.x);
        a2 += wc * bflo(uc.y); a3 += wc * bfhi(uc.y);
        a0 += wd * bflo(ud.x); a1 += wd * bfhi(ud.x);
        a2 += wd * bflo(ud.y); a3 += wd * bfhi(ud.y);
    }
    for (; s < e2; ++s) {
        const int2 ea = rw[s];
        const uint2 ua = *(const uint2*)(H + (size_t)ea.x * 64 + l * 4);
        const float wa = __int_as_float(ea.y);
        a0 += wa * bflo(ua.x); a1 += wa * bfhi(ua.x);
        a2 += wa * bflo(ua.y); a3 += wa * bfhi(ua.y);
    }
    const float4 cb = *(const float4*)(CB + l * 4);
    if (MODE == 1) {
        ushort4 o;
        o.x = f2bf(relu(a0 + cb.x)); o.y = f2bf(relu(a1 + cb.y));
        o.z = f2bf(relu(a2 + cb.z)); o.w = f2bf(relu(a3 + cb.w));
        *(ushort4*)(OXB + (size_t)d * 64 + l * 4) = o;
    } else {
        const float4 x5v = *(const float4*)(X5 + (size_t)d * 64 + l * 4);
        const float v0 = x5v.x + relu(a0 + cb.x);
        const float v1 = x5v.y + relu(a1 + cb.y);
        const float v2 = x5v.z + relu(a2 + cb.z);
        const float v3 = x5v.w + relu(a3 + cb.w);
        const float4 w9 = *(const float4*)(FC2W + l * 4);
        const float4 wX = *(const float4*)(C3W + l * 4);
        float p9 = v0 * w9.x + v1 * w9.y + v2 * w9.z + v3 * w9.w;
        float p10 = v0 * wX.x + v1 * wX.y + v2 * wX.z + v3 * wX.w;
#pragma unroll
        for (int m = 1; m < 16; m <<= 1) {
            p9 += __shfl_xor(p9, m, 64);
            p10 += __shfl_xor(p10, m, 64);
        }
        if (l == 0) {
            OUT[d] = p9 + FC2B[0] + C3B[0];
            H3[d] = p10;
        }
    }
}

// ---- final CSR gather, 1 feature ----
__global__ __launch_bounds__(256) void k_gather1f(const int* __restrict__ start,
                                                  const int* __restrict__ degi,
                                                  const int2* __restrict__ rw,
                                                  const float* __restrict__ H3,
                                                  float* __restrict__ OUT, int N) {
    const int d = blockIdx.x * 256 + threadIdx.x;
    if (d >= N) return;
    int s = start[d];
    const int e2 = s + degi[d];
    float acc = 0.f;
    for (; s + 3 < e2; s += 4) {
        const int2 a = rw[s], b = rw[s + 1], c = rw[s + 2], e = rw[s + 3];
        acc += H3[a.x] * __int_as_float(a.y);
        acc += H3[b.x] * __int_as_float(b.y);
        acc += H3[c.x] * __int_as_float(c.y);
        acc += H3[e.x] * __int_as_float(e.y);
    }
    for (; s < e2; ++s) {
        const int2 a = rw[s];
        acc += H3[a.x] * __int_as_float(a.y);
    }
    OUT[d] += acc;
}

extern "C" void kernel_launch(void* const* d_in, const int* in_sizes, int n_in,
                              void* d_out, int out_size, void* d_ws, size_t ws_size,
                              hipStream_t stream) {
    const float* x    = (const float*)d_in[0];
    const float* fcw  = (const float*)d_in[1];
    const float* fcb  = (const float*)d_in[2];
    const float* c1w  = (const float*)d_in[3];
    const float* c1b  = (const float*)d_in[4];
    const float* f1w  = (const float*)d_in[5];
    const float* f1b  = (const float*)d_in[6];
    const float* c2w  = (const float*)d_in[7];
    const float* c2b  = (const float*)d_in[8];
    const float* f2w  = (const float*)d_in[9];
    const float* f2b  = (const float*)d_in[10];
    const float* c3w  = (const float*)d_in[11];
    const float* c3b  = (const float*)d_in[12];
    const int*   ei   = (const int*)d_in[13];

    const int N = in_sizes[0] / IN_DIM;
    const int E = in_sizes[13] / 2;
    const int* row = ei;
    const int* col = ei + E;
    float* out = (float*)d_out;

    const int NR = (N + RB - 1) >> RB_SHIFT;

    const size_t Npad = ((size_t)N + 127) & ~(size_t)127;
    const size_t NF = (size_t)N * 64;
    const size_t REG = (size_t)NR * MAXBIN;
    int*   binCur = (int*)d_ws;                          // NBMAX
    int*   degi   = binCur + NBMAX;                      // N
    float* dinv   = (float*)(degi + Npad);               // N
    int*   start  = (int*)(dinv + Npad);                 // N
    unsigned short* Wt = (unsigned short*)(start + Npad);// 2*16384 bf16
    int2*  part   = (int2*)(Wt + 2 * 16384);             // NR*MAXBIN
    int2*  rw     = part + REG;                          // NR*MAXBIN (region CSR)
    unsigned short* x1bf = (unsigned short*)(rw + REG);  // N*64 bf16
    unsigned short* h1   = x1bf + NF;                    // N*64 bf16 (reused as h2)
    unsigned short* x2bf = h1 + NF;                      // N*64 bf16
    float* x5     = (float*)(x2bf + NF);                 // N*64 f32
    float* h3     = x5 + NF;                             // N f32
    unsigned short* h2 = h1;

    const int gN = (N + 255) / 256;
    const int gG = (N + 63) / 64;
    const int gW = (N + 15) / 16;
    const int gP = (E + PCH - 1) / PCH;

    // --- CSR build + weight repack (9 dispatches total for whole net) ---
    k_wprep<<<16, 256, 0, stream>>>(fcw, c1w, f1w, c2w, Wt, binCur, NR);
    k_part<<<gP, 256, 0, stream>>>(row, col, binCur, part, E);
    k_csrA<<<NR, 256, 0, stream>>>(binCur, part, degi, dinv, start, N);
    k_csrB<<<NR, 256, 0, stream>>>(binCur, part, start, dinv, rw, N);

    // --- layer 1 ---
    k_gemm<1><<<gG, 256, 0, stream>>>(x, nullptr, nullptr, Wt, fcb,
                                      nullptr, x1bf, h1, N);
    k_gather<1><<<gW, 256, 0, stream>>>(start, degi, rw, h1, c1b, x2bf,
                                        nullptr, nullptr, nullptr, nullptr,
                                        nullptr, nullptr, nullptr, N);

    // --- layer 2 ---
    k_gemm<2><<<gG, 256, 0, stream>>>(nullptr, x1bf, x2bf, Wt + 16384, f1b,
                                      x5, nullptr, h2, N);
    // --- layer 3 (combine fused into gather) ---
    k_gather<2><<<gW, 256, 0, stream>>>(start, degi, rw, h2, c2b, nullptr,
                                        x5, f2w, f2b, c3w, c3b, h3, out, N);
    k_gather1f<<<gN, 256, 0, stream>>>(start, degi, rw, h3, out, N);
}

// Round 11
// 260.172 us; speedup vs baseline: 1.9563x; 1.0974x over previous
//
#include <hip/hip_runtime.h>

#define IN_DIM 128
#define HID 64
#define RB_SHIFT 10 // 1024 nodes per dest-range
#define RB 1024
#define NBMAX 128   // max ranges (N <= 128K)
#define MAXBIN 16384 // capacity per range bin region (mean ~12.3K)
#define PCH 2048    // edges per k_part block

typedef short bf16x8 __attribute__((ext_vector_type(8)));
typedef float f32x4  __attribute__((ext_vector_type(4)));

__device__ __forceinline__ float relu(float v) { return v > 0.f ? v : 0.f; }

// fp32 -> bf16 round-to-nearest-even
__device__ __forceinline__ unsigned short f2bf(float f) {
    unsigned u = __float_as_uint(f);
    u += 0x7FFFu + ((u >> 16) & 1u);
    return (unsigned short)(u >> 16);
}
__device__ __forceinline__ float bflo(unsigned u) { return __uint_as_float(u << 16); }
__device__ __forceinline__ float bfhi(unsigned u) { return __uint_as_float(u & 0xFFFF0000u); }

// ---- weight repack into MFMA B-frag order (+ binCursor init, block 0) ----
__global__ __launch_bounds__(256) void k_wprep(const float* __restrict__ W1a,
                                               const float* __restrict__ W2a,
                                               const float* __restrict__ W1b,
                                               const float* __restrict__ W2b,
                                               unsigned short* __restrict__ Wt,
                                               int* __restrict__ binCursor, int NR) {
    if (blockIdx.x == 0 && threadIdx.x < NR) binCursor[threadIdx.x] = threadIdx.x * MAXBIN;
    const int t = blockIdx.x * 256 + threadIdx.x;   // (layer,kc,c,lane)
    if (t >= 2 * 4 * 8 * 64) return;
    const int lane = t & 63;
    const int c = (t >> 6) & 7;
    const int kc = (t >> 9) & 3;
    const int layer = t >> 11;
    const int col = c * 16 + (lane & 15);
    const int k0 = kc * 32 + (lane >> 4) * 8;
    const float* W1 = layer ? W1b : W1a;
    const float* W2 = layer ? W2b : W2a;
    const float* src = (col < 64) ? (W1 + col) : (W2 + (col - 64));
    unsigned short v[8];
#pragma unroll
    for (int j = 0; j < 8; j++) v[j] = f2bf(src[(size_t)(k0 + j) * 64]);
    *(ushort4*)(Wt + (size_t)t * 8) = make_ushort4(v[0], v[1], v[2], v[3]);
    *(ushort4*)(Wt + (size_t)t * 8 + 4) = make_ushort4(v[4], v[5], v[6], v[7]);
}

// ---- phase 1: partition edges into dest-ranges ----
__global__ __launch_bounds__(256) void k_part(const int* __restrict__ row,
                                              const int* __restrict__ col,
                                              int* __restrict__ binCursor,
                                              int2* __restrict__ part, int E) {
    __shared__ int lcur[NBMAX], gbase[NBMAX];
    const int tid = threadIdx.x;
    const int e0 = blockIdx.x * PCH;
    const int cnt = min(PCH, E - e0);
    if (tid < NBMAX) lcur[tid] = 0;
    __syncthreads();
    int rr[8], cc[8], pp[8];
    if (cnt == PCH) {
#pragma unroll
        for (int h = 0; h < 2; h++) {
            const int4 c4 = *(const int4*)(col + e0 + h * 1024 + tid * 4);
            const int4 r4 = *(const int4*)(row + e0 + h * 1024 + tid * 4);
            cc[h * 4 + 0] = c4.x; cc[h * 4 + 1] = c4.y;
            cc[h * 4 + 2] = c4.z; cc[h * 4 + 3] = c4.w;
            rr[h * 4 + 0] = r4.x; rr[h * 4 + 1] = r4.y;
            rr[h * 4 + 2] = r4.z; rr[h * 4 + 3] = r4.w;
        }
    } else {
#pragma unroll
        for (int j = 0; j < 8; j++) {
            const int e = e0 + j * 256 + tid;
            if (e < e0 + cnt) { rr[j] = row[e]; cc[j] = col[e]; }
            else cc[j] = -1;
        }
    }
#pragma unroll
    for (int j = 0; j < 8; j++)
        if (cc[j] >= 0) pp[j] = atomicAdd(&lcur[cc[j] >> RB_SHIFT], 1);
    __syncthreads();
    if (tid < NBMAX && lcur[tid] > 0)
        gbase[tid] = atomicAdd(&binCursor[tid], lcur[tid]);
    __syncthreads();
#pragma unroll
    for (int j = 0; j < 8; j++)
        if (cc[j] >= 0)
            part[gbase[cc[j] >> RB_SHIFT] + pp[j]] = make_int2(rr[j], cc[j]);
}

// ---- phase 2 (merged): per-range histogram + local scan -> degi/dinv/start,
// then in-region placement with LDS cursors writing rs (row only — norm is
// factored: H rows pre-scaled by dinv[row], dinv[col] applied per-dest) ----
__global__ __launch_bounds__(256) void k_csr(const int* __restrict__ binCursor,
                                             const int2* __restrict__ part,
                                             int* __restrict__ degi,
                                             float* __restrict__ dinv,
                                             int* __restrict__ start,
                                             int* __restrict__ rs, int N) {
    __shared__ int cnt[RB];
    __shared__ int psum[256];
    const int b = blockIdx.x;
    const int lo = b << RB_SHIFT;
    const int tid = threadIdx.x;
    for (int i = tid; i < RB; i += 256) cnt[i] = 0;
    __syncthreads();
    const int base = b * MAXBIN;
    const int tot = binCursor[b] - base;
    for (int i = tid; i < tot; i += 256)
        atomicAdd(&cnt[part[base + i].y - lo], 1);
    __syncthreads();
    const int i0 = tid * 4;
    const int c0 = cnt[i0], c1 = cnt[i0 + 1], c2 = cnt[i0 + 2], c3 = cnt[i0 + 3];
    const int s = c0 + c1 + c2 + c3;
    psum[tid] = s;
    __syncthreads();
    for (int off = 1; off < 256; off <<= 1) {
        int t = (tid >= off) ? psum[tid - off] : 0;
        __syncthreads();
        psum[tid] += t;
        __syncthreads();
    }
    const int e = psum[tid] - s;   // exclusive
    const int offs[4] = {e, e + c0, e + c0 + c1, e + c0 + c1 + c2};
    const int cs[4] = {c0, c1, c2, c3};
#pragma unroll
    for (int j = 0; j < 4; j++) {
        const int n = lo + i0 + j;
        if (n < N) {
            degi[n] = cs[j];
            start[n] = base + offs[j];
            dinv[n] = cs[j] > 0 ? rsqrtf((float)cs[j]) : 0.f;
        }
        cnt[i0 + j] = base + offs[j];   // becomes LDS cursor
    }
    __syncthreads();
    for (int i = tid; i < tot; i += 256) {
        const int2 v = part[base + i];
        const int pos = atomicAdd(&cnt[v.y - lo], 1);
        rs[pos] = v.x;
    }
}

// ---- MFMA dual GEMM ----
// LAYER 1: A = X fp32 (cvt bf16); O1 = x1 bf16 (relu+bias), O2 = h1' bf16 (×dinv).
// LAYER 2: A = [x1bf | x2bf] direct bf16; O1 = x5 fp32, O2 = h2' bf16 (×dinv).
template <int LAYER>
__global__ __launch_bounds__(256) void k_gemm(const float* __restrict__ XF,
                                              const unsigned short* __restrict__ X1B,
                                              const unsigned short* __restrict__ X2B,
                                              const unsigned short* __restrict__ Wt,
                                              const float* __restrict__ B1,
                                              const float* __restrict__ dinv,
                                              float* __restrict__ O1f,
                                              unsigned short* __restrict__ O1b,
                                              unsigned short* __restrict__ O2,
                                              int N) {
    const int tid = threadIdx.x;
    const int wave = tid >> 6;
    const int lane = tid & 63;
    const int quad = lane >> 4;
    const int lm = lane & 15;
    const int n0 = blockIdx.x * 64 + wave * 16;
    if (n0 >= N) return;
    const int nrow = min(n0 + lm, N - 1);

    f32x4 acc[8];
#pragma unroll
    for (int c = 0; c < 8; c++) acc[c] = (f32x4){0.f, 0.f, 0.f, 0.f};

#pragma unroll
    for (int kc = 0; kc < 4; kc++) {
        const int k0 = kc * 32 + quad * 8;
        bf16x8 a;
        if (LAYER == 1) {
            const float* s = XF + (size_t)nrow * IN_DIM + k0;
            const float4 q0 = *(const float4*)s;
            const float4 q1 = *(const float4*)(s + 4);
            a[0] = (short)f2bf(q0.x); a[1] = (short)f2bf(q0.y);
            a[2] = (short)f2bf(q0.z); a[3] = (short)f2bf(q0.w);
            a[4] = (short)f2bf(q1.x); a[5] = (short)f2bf(q1.y);
            a[6] = (short)f2bf(q1.z); a[7] = (short)f2bf(q1.w);
        } else {
            const unsigned short* s = (kc < 2) ? (X1B + (size_t)nrow * 64 + k0)
                                               : (X2B + (size_t)nrow * 64 + (k0 - 64));
            a = *(const bf16x8*)s;
        }
#pragma unroll
        for (int c = 0; c < 8; c++) {
            const bf16x8 b = *(const bf16x8*)(Wt + (size_t)((kc * 8 + c) * 64 + lane) * 8);
            acc[c] = __builtin_amdgcn_mfma_f32_16x16x32_bf16(a, b, acc[c], 0, 0, 0);
        }
    }

    const int nb = n0 + quad * 4;
    float dvv[4];
#pragma unroll
    for (int r = 0; r < 4; r++) dvv[r] = (nb + r < N) ? dinv[nb + r] : 0.f;
#pragma unroll
    for (int c = 0; c < 4; c++) {
        const int col = c * 16 + lm;
        const float b = B1[col];
#pragma unroll
        for (int r = 0; r < 4; r++) {
            const int n = nb + r;
            if (n < N) {
                const float v = relu(acc[c][r] + b);
                if (LAYER == 1) O1b[(size_t)n * 64 + col] = f2bf(v);
                else            O1f[(size_t)n * 64 + col] = v;
            }
        }
    }
#pragma unroll
    for (int c = 4; c < 8; c++) {
        const int col = (c - 4) * 16 + lm;
#pragma unroll
        for (int r = 0; r < 4; r++) {
            const int n = nb + r;
            if (n < N) O2[(size_t)n * 64 + col] = f2bf(acc[c][r] * dvv[r]);
        }
    }
}

// ---- CSR gather, bf16 H' (pre-scaled by dinv[row]); 8 lanes/dest,
// 8 feats/lane (16 B uint4 load), unroll 4 -> 32 loads in flight per wave.
// MODE 1: x2 = relu(dinv[d]*acc + CB) bf16.  MODE 2: fused combine+projections.
template <int MODE>
__global__ __launch_bounds__(256) void k_gather(const int* __restrict__ start,
                                                const int* __restrict__ degi,
                                                const int* __restrict__ rs,
                                                const unsigned short* __restrict__ H,
                                                const float* __restrict__ dinv,
                                                const float* __restrict__ CB,
                                                unsigned short* __restrict__ OXB,
                                                const float* __restrict__ X5,
                                                const float* __restrict__ FC2W,
                                                const float* __restrict__ FC2B,
                                                const float* __restrict__ C3W,
                                                const float* __restrict__ C3B,
                                                float* __restrict__ H3,
                                                float* __restrict__ OUT, int N) {
    const int l = threadIdx.x & 7;                // feats 8l..8l+7
    const int d = blockIdx.x * 32 + (threadIdx.x >> 3);
    if (d >= N) return;
    int s = start[d];
    const int e2 = s + degi[d];
    float a0 = 0.f, a1 = 0.f, a2 = 0.f, a3 = 0.f;
    float a4 = 0.f, a5 = 0.f, a6 = 0.f, a7 = 0.f;
#define ACC8(u)                                                          \
    a0 += bflo(u.x); a1 += bfhi(u.x); a2 += bflo(u.y); a3 += bfhi(u.y);  \
    a4 += bflo(u.z); a5 += bfhi(u.z); a6 += bflo(u.w); a7 += bfhi(u.w);
    for (; s + 3 < e2; s += 4) {
        const int4 e4 = *(const int4*)(rs + s);
        const uint4 ua = *(const uint4*)(H + (size_t)e4.x * 64 + l * 8);
        const uint4 ub = *(const uint4*)(H + (size_t)e4.y * 64 + l * 8);
        const uint4 uc = *(const uint4*)(H + (size_t)e4.z * 64 + l * 8);
        const uint4 ud = *(const uint4*)(H + (size_t)e4.w * 64 + l * 8);
        ACC8(ua) ACC8(ub) ACC8(uc) ACC8(ud)
    }
    for (; s < e2; ++s) {
        const uint4 ua = *(const uint4*)(H + (size_t)rs[s] * 64 + l * 8);
        ACC8(ua)
    }
#undef ACC8
    const float dd = dinv[d];
    const float4 cba = *(const float4*)(CB + l * 8);
    const float4 cbb = *(const float4*)(CB + l * 8 + 4);
    const float r0 = relu(dd * a0 + cba.x), r1 = relu(dd * a1 + cba.y);
    const float r2 = relu(dd * a2 + cba.z), r3 = relu(dd * a3 + cba.w);
    const float r4 = relu(dd * a4 + cbb.x), r5 = relu(dd * a5 + cbb.y);
    const float r6 = relu(dd * a6 + cbb.z), r7 = relu(dd * a7 + cbb.w);
    if (MODE == 1) {
        uint4 o;
        o.x = (unsigned)f2bf(r0) | ((unsigned)f2bf(r1) << 16);
        o.y = (unsigned)f2bf(r2) | ((unsigned)f2bf(r3) << 16);
        o.z = (unsigned)f2bf(r4) | ((unsigned)f2bf(r5) << 16);
        o.w = (unsigned)f2bf(r6) | ((unsigned)f2bf(r7) << 16);
        *(uint4*)(OXB + (size_t)d * 64 + l * 8) = o;
    } else {
        const float4 xa = *(const float4*)(X5 + (size_t)d * 64 + l * 8);
        const float4 xb = *(const float4*)(X5 + (size_t)d * 64 + l * 8 + 4);
        const float v0 = xa.x + r0, v1 = xa.y + r1, v2 = xa.z + r2, v3 = xa.w + r3;
        const float v4 = xb.x + r4, v5 = xb.y + r5, v6 = xb.z + r6, v7 = xb.w + r7;
        const float4 w9a = *(const float4*)(FC2W + l * 8);
        const float4 w9b = *(const float4*)(FC2W + l * 8 + 4);
        const float4 wXa = *(const float4*)(C3W + l * 8);
        const float4 wXb = *(const float4*)(C3W + l * 8 + 4);
        float p9 = v0 * w9a.x + v1 * w9a.y + v2 * w9a.z + v3 * w9a.w
                 + v4 * w9b.x + v5 * w9b.y + v6 * w9b.z + v7 * w9b.w;
        float p10 = v0 * wXa.x + v1 * wXa.y + v2 * wXa.z + v3 * wXa.w
                  + v4 * wXb.x + v5 * wXb.y + v6 * wXb.z + v7 * wXb.w;
#pragma unroll
        for (int m = 1; m < 8; m <<= 1) {
            p9 += __shfl_xor(p9, m, 64);
            p10 += __shfl_xor(p10, m, 64);
        }
        if (l == 0) {
            OUT[d] = p9 + FC2B[0] + C3B[0];
            H3[d] = p10 * dd;   // pre-scale by dinv[row] for gather1f
        }
    }
}

// ---- final CSR gather, 1 feature (H3 pre-scaled; ×dinv[d] at end) ----
__global__ __launch_bounds__(256) void k_gather1f(const int* __restrict__ start,
                                                  const int* __restrict__ degi,
                                                  const int* __restrict__ rs,
                                                  const float* __restrict__ H3,
                                                  const float* __restrict__ dinv,
                                                  float* __restrict__ OUT, int N) {
    const int d = blockIdx.x * 256 + threadIdx.x;
    if (d >= N) return;
    int s = start[d];
    const int e2 = s + degi[d];
    float acc = 0.f;
    for (; s + 3 < e2; s += 4) {
        const int4 e4 = *(const int4*)(rs + s);   // may straddle: rs is int, ok unaligned? use scalars
        acc += H3[e4.x] + H3[e4.y] + H3[e4.z] + H3[e4.w];
    }
    for (; s < e2; ++s) acc += H3[rs[s]];
    OUT[d] += acc * dinv[d];
}

extern "C" void kernel_launch(void* const* d_in, const int* in_sizes, int n_in,
                              void* d_out, int out_size, void* d_ws, size_t ws_size,
                              hipStream_t stream) {
    const float* x    = (const float*)d_in[0];
    const float* fcw  = (const float*)d_in[1];
    const float* fcb  = (const float*)d_in[2];
    const float* c1w  = (const float*)d_in[3];
    const float* c1b  = (const float*)d_in[4];
    const float* f1w  = (const float*)d_in[5];
    const float* f1b  = (const float*)d_in[6];
    const float* c2w  = (const float*)d_in[7];
    const float* c2b  = (const float*)d_in[8];
    const float* f2w  = (const float*)d_in[9];
    const float* f2b  = (const float*)d_in[10];
    const float* c3w  = (const float*)d_in[11];
    const float* c3b  = (const float*)d_in[12];
    const int*   ei   = (const int*)d_in[13];

    const int N = in_sizes[0] / IN_DIM;
    const int E = in_sizes[13] / 2;
    const int* row = ei;
    const int* col = ei + E;
    float* out = (float*)d_out;

    const int NR = (N + RB - 1) >> RB_SHIFT;

    const size_t Npad = ((size_t)N + 127) & ~(size_t)127;
    const size_t NF = (size_t)N * 64;
    const size_t REG = (size_t)NR * MAXBIN;
    int*   binCur = (int*)d_ws;                          // NBMAX
    int*   degi   = binCur + NBMAX;                      // N
    float* dinv   = (float*)(degi + Npad);               // N
    int*   start  = (int*)(dinv + Npad);                 // N
    unsigned short* Wt = (unsigned short*)(start + Npad);// 2*16384 bf16
    int2*  part   = (int2*)(Wt + 2 * 16384);             // NR*MAXBIN int2
    int*   rs     = (int*)(part + REG);                  // NR*MAXBIN int
    unsigned short* x1bf = (unsigned short*)(rs + REG);  // N*64 bf16
    unsigned short* h1   = x1bf + NF;                    // N*64 bf16 (reused as h2)
    unsigned short* x2bf = h1 + NF;                      // N*64 bf16
    float* x5     = (float*)(x2bf + NF);                 // N*64 f32
    float* h3     = x5 + NF;                             // N f32 (pre-scaled)
    unsigned short* h2 = h1;

    const int gN = (N + 255) / 256;
    const int gG = (N + 63) / 64;
    const int gW = (N + 31) / 32;
    const int gP = (E + PCH - 1) / PCH;

    // --- CSR build + weight repack ---
    k_wprep<<<16, 256, 0, stream>>>(fcw, c1w, f1w, c2w, Wt, binCur, NR);
    k_part<<<gP, 256, 0, stream>>>(row, col, binCur, part, E);
    k_csr<<<NR, 256, 0, stream>>>(binCur, part, degi, dinv, start, rs, N);

    // --- layer 1 ---
    k_gemm<1><<<gG, 256, 0, stream>>>(x, nullptr, nullptr, Wt, fcb, dinv,
                                      nullptr, x1bf, h1, N);
    k_gather<1><<<gW, 256, 0, stream>>>(start, degi, rs, h1, dinv, c1b, x2bf,
                                        nullptr, nullptr, nullptr, nullptr,
                                        nullptr, nullptr, nullptr, N);

    // --- layer 2 ---
    k_gemm<2><<<gG, 256, 0, stream>>>(nullptr, x1bf, x2bf, Wt + 16384, f1b, dinv,
                                      x5, nullptr, h2, N);
    // --- layer 3 (combine fused into gather) ---
    k_gather<2><<<gW, 256, 0, stream>>>(start, degi, rs, h2, dinv, c2b, nullptr,
                                        x5, f2w, f2b, c3w, c3b, h3, out, N);
    k_gather1f<<<gN, 256, 0, stream>>>(start, degi, rs, h3, dinv, out, N);
}

// Round 12
// 252.435 us; speedup vs baseline: 2.0163x; 1.0307x over previous
//
#include <hip/hip_runtime.h>

#define IN_DIM 128
#define RB_SHIFT 10 // 1024 nodes per dest-range
#define RB 1024
#define NBMAX 128   // max ranges (N <= 128K)
#define MAXBIN 16384 // capacity per range bin region (mean ~12.3K)
#define PCH 2048    // edges per k_part block

typedef short bf16x8 __attribute__((ext_vector_type(8)));
typedef float f32x4  __attribute__((ext_vector_type(4)));

__device__ __forceinline__ float relu(float v) { return v > 0.f ? v : 0.f; }

// fp32 -> bf16 round-to-nearest-even
__device__ __forceinline__ unsigned short f2bf(float f) {
    unsigned u = __float_as_uint(f);
    u += 0x7FFFu + ((u >> 16) & 1u);
    return (unsigned short)(u >> 16);
}
__device__ __forceinline__ float bflo(unsigned u) { return __uint_as_float(u << 16); }
__device__ __forceinline__ float bfhi(unsigned u) { return __uint_as_float(u & 0xFFFF0000u); }

// ---- weight repack into MFMA B-frag order (+ binCursor init, block 0) ----
// Wt[layer][kc][c][lane][j] bf16 : B[k=kc*32+(lane>>4)*8+j][col=c*16+(lane&15)]
__global__ __launch_bounds__(256) void k_wprep(const float* __restrict__ W1a,
                                               const float* __restrict__ W2a,
                                               const float* __restrict__ W1b,
                                               const float* __restrict__ W2b,
                                               unsigned short* __restrict__ Wt,
                                               int* __restrict__ binCursor, int NR) {
    if (blockIdx.x == 0 && threadIdx.x < NR) binCursor[threadIdx.x] = threadIdx.x * MAXBIN;
    const int t = blockIdx.x * 256 + threadIdx.x;   // (layer,kc,c,lane)
    if (t >= 2 * 4 * 8 * 64) return;
    const int lane = t & 63;
    const int c = (t >> 6) & 7;
    const int kc = (t >> 9) & 3;
    const int layer = t >> 11;
    const int col = c * 16 + (lane & 15);
    const int k0 = kc * 32 + (lane >> 4) * 8;
    const float* W1 = layer ? W1b : W1a;
    const float* W2 = layer ? W2b : W2a;
    const float* src = (col < 64) ? (W1 + col) : (W2 + (col - 64));
    unsigned short v[8];
#pragma unroll
    for (int j = 0; j < 8; j++) v[j] = f2bf(src[(size_t)(k0 + j) * 64]);
    *(ushort4*)(Wt + (size_t)t * 8) = make_ushort4(v[0], v[1], v[2], v[3]);
    *(ushort4*)(Wt + (size_t)t * 8 + 4) = make_ushort4(v[4], v[5], v[6], v[7]);
}

// ---- phase 1: partition edges into dest-ranges; entry packed (row<<10)|li ----
__global__ __launch_bounds__(256) void k_part(const int* __restrict__ row,
                                              const int* __restrict__ col,
                                              int* __restrict__ binCursor,
                                              int* __restrict__ part, int E) {
    __shared__ int lcur[NBMAX], gbase[NBMAX];
    const int tid = threadIdx.x;
    const int e0 = blockIdx.x * PCH;
    const int cnt = min(PCH, E - e0);
    if (tid < NBMAX) lcur[tid] = 0;
    __syncthreads();
    int rr[8], cc[8], pp[8];
    if (cnt == PCH) {
#pragma unroll
        for (int h = 0; h < 2; h++) {
            const int4 c4 = *(const int4*)(col + e0 + h * 1024 + tid * 4);
            const int4 r4 = *(const int4*)(row + e0 + h * 1024 + tid * 4);
            cc[h * 4 + 0] = c4.x; cc[h * 4 + 1] = c4.y;
            cc[h * 4 + 2] = c4.z; cc[h * 4 + 3] = c4.w;
            rr[h * 4 + 0] = r4.x; rr[h * 4 + 1] = r4.y;
            rr[h * 4 + 2] = r4.z; rr[h * 4 + 3] = r4.w;
        }
    } else {
#pragma unroll
        for (int j = 0; j < 8; j++) {
            const int e = e0 + j * 256 + tid;
            if (e < e0 + cnt) { rr[j] = row[e]; cc[j] = col[e]; }
            else cc[j] = -1;
        }
    }
#pragma unroll
    for (int j = 0; j < 8; j++)
        if (cc[j] >= 0) pp[j] = atomicAdd(&lcur[cc[j] >> RB_SHIFT], 1);
    __syncthreads();
    if (tid < NBMAX && lcur[tid] > 0)
        gbase[tid] = atomicAdd(&binCursor[tid], lcur[tid]);
    __syncthreads();
#pragma unroll
    for (int j = 0; j < 8; j++)
        if (cc[j] >= 0)
            part[gbase[cc[j] >> RB_SHIFT] + pp[j]] =
                (rr[j] << RB_SHIFT) | (cc[j] & (RB - 1));
}

// ---- phase 2 (merged): per-range histogram + local scan -> degi/dinv/start,
// then in-region placement with LDS cursors writing rs (row only) ----
__global__ __launch_bounds__(256) void k_csr(const int* __restrict__ binCursor,
                                             const int* __restrict__ part,
                                             int* __restrict__ degi,
                                             float* __restrict__ dinv,
                                             int* __restrict__ start,
                                             int* __restrict__ rs, int N) {
    __shared__ int cnt[RB];
    __shared__ int psum[256];
    const int b = blockIdx.x;
    const int lo = b << RB_SHIFT;
    const int tid = threadIdx.x;
    for (int i = tid; i < RB; i += 256) cnt[i] = 0;
    __syncthreads();
    const int base = b * MAXBIN;
    const int tot = binCursor[b] - base;
    for (int i = tid; i < tot; i += 256)
        atomicAdd(&cnt[part[base + i] & (RB - 1)], 1);
    __syncthreads();
    const int i0 = tid * 4;
    const int c0 = cnt[i0], c1 = cnt[i0 + 1], c2 = cnt[i0 + 2], c3 = cnt[i0 + 3];
    const int s = c0 + c1 + c2 + c3;
    psum[tid] = s;
    __syncthreads();
    for (int off = 1; off < 256; off <<= 1) {
        int t = (tid >= off) ? psum[tid - off] : 0;
        __syncthreads();
        psum[tid] += t;
        __syncthreads();
    }
    const int e = psum[tid] - s;   // exclusive
    const int offs[4] = {e, e + c0, e + c0 + c1, e + c0 + c1 + c2};
    const int cs[4] = {c0, c1, c2, c3};
#pragma unroll
    for (int j = 0; j < 4; j++) {
        const int n = lo + i0 + j;
        if (n < N) {
            degi[n] = cs[j];
            start[n] = base + offs[j];
            dinv[n] = cs[j] > 0 ? rsqrtf((float)cs[j]) : 0.f;
        }
        cnt[i0 + j] = base + offs[j];   // becomes LDS cursor
    }
    __syncthreads();
    for (int i = tid; i < tot; i += 256) {
        const int v = part[base + i];
        const int pos = atomicAdd(&cnt[v & (RB - 1)], 1);
        rs[pos] = v >> RB_SHIFT;
    }
}

// ---- layer-1 MFMA dual GEMM: x1 = relu(X@fcw+fcb) bf16, h1' = (X@c1w)*dinv bf16 ----
__global__ __launch_bounds__(256) void k_gemm1(const float* __restrict__ XF,
                                               const unsigned short* __restrict__ Wt,
                                               const float* __restrict__ B1,
                                               const float* __restrict__ dinv,
                                               unsigned short* __restrict__ O1b,
                                               unsigned short* __restrict__ O2,
                                               int N) {
    const int tid = threadIdx.x;
    const int wave = tid >> 6;
    const int lane = tid & 63;
    const int quad = lane >> 4;
    const int lm = lane & 15;
    const int n0 = blockIdx.x * 64 + wave * 16;
    if (n0 >= N) return;
    const int nrow = min(n0 + lm, N - 1);

    f32x4 acc[8];
#pragma unroll
    for (int c = 0; c < 8; c++) acc[c] = (f32x4){0.f, 0.f, 0.f, 0.f};

#pragma unroll
    for (int kc = 0; kc < 4; kc++) {
        const int k0 = kc * 32 + quad * 8;
        const float* s = XF + (size_t)nrow * IN_DIM + k0;
        const float4 q0 = *(const float4*)s;
        const float4 q1 = *(const float4*)(s + 4);
        bf16x8 a;
        a[0] = (short)f2bf(q0.x); a[1] = (short)f2bf(q0.y);
        a[2] = (short)f2bf(q0.z); a[3] = (short)f2bf(q0.w);
        a[4] = (short)f2bf(q1.x); a[5] = (short)f2bf(q1.y);
        a[6] = (short)f2bf(q1.z); a[7] = (short)f2bf(q1.w);
#pragma unroll
        for (int c = 0; c < 8; c++) {
            const bf16x8 b = *(const bf16x8*)(Wt + (size_t)((kc * 8 + c) * 64 + lane) * 8);
            acc[c] = __builtin_amdgcn_mfma_f32_16x16x32_bf16(a, b, acc[c], 0, 0, 0);
        }
    }

    const int nb = n0 + quad * 4;
    float dvv[4];
#pragma unroll
    for (int r = 0; r < 4; r++) dvv[r] = (nb + r < N) ? dinv[nb + r] : 0.f;
#pragma unroll
    for (int c = 0; c < 4; c++) {
        const int col = c * 16 + lm;
        const float b = B1[col];
#pragma unroll
        for (int r = 0; r < 4; r++) {
            const int n = nb + r;
            if (n < N) O1b[(size_t)n * 64 + col] = f2bf(relu(acc[c][r] + b));
        }
    }
#pragma unroll
    for (int c = 4; c < 8; c++) {
        const int col = (c - 4) * 16 + lm;
#pragma unroll
        for (int r = 0; r < 4; r++) {
            const int n = nb + r;
            if (n < N) O2[(size_t)n * 64 + col] = f2bf(acc[c][r] * dvv[r]);
        }
    }
}

#define ACC8(u)                                                          \
    a0 += bflo(u.x); a1 += bfhi(u.x); a2 += bflo(u.y); a3 += bfhi(u.y);  \
    a4 += bflo(u.z); a5 += bfhi(u.z); a6 += bflo(u.w); a7 += bfhi(u.w);

// ---- FUSED gather1 + gemm2 ----
// Phase A: 8 lanes/dest gather h1' rows for 32 dests; x2 = relu(dinv*acc+c1b)
//          into LDS (stride-72 rows: 8 lanes per 4-bank group -> even, no penalty).
// Phase B: dual MFMA for the same 32 nodes: A = [x1bf global | x2 LDS],
//          B-frags L2-hot. x5 bf16, h2' bf16 (×dinv). Kills x2 global round-trip.
__global__ __launch_bounds__(256) void k_gfuse(const int* __restrict__ start,
                                               const int* __restrict__ degi,
                                               const int* __restrict__ rs,
                                               const unsigned short* __restrict__ H,
                                               const float* __restrict__ dinv,
                                               const float* __restrict__ CB,
                                               const unsigned short* __restrict__ X1B,
                                               const unsigned short* __restrict__ Wt,
                                               const float* __restrict__ B1,
                                               unsigned short* __restrict__ X5B,
                                               unsigned short* __restrict__ H2,
                                               int N) {
    __shared__ __align__(16) unsigned short x2s[32][72];
    const int tid = threadIdx.x;
    const int l = tid & 7;                 // feats 8l..8l+7
    const int di = tid >> 3;               // 0..31 local dest
    const int d = blockIdx.x * 32 + di;

    uint4 ov = make_uint4(0u, 0u, 0u, 0u);
    if (d < N) {
        int s = start[d];
        const int e2 = s + degi[d];
        float a0 = 0.f, a1 = 0.f, a2 = 0.f, a3 = 0.f;
        float a4 = 0.f, a5 = 0.f, a6 = 0.f, a7 = 0.f;
        for (; s + 3 < e2; s += 4) {
            const int4 e4 = *(const int4*)(rs + s);
            const uint4 ua = *(const uint4*)(H + (size_t)e4.x * 64 + l * 8);
            const uint4 ub = *(const uint4*)(H + (size_t)e4.y * 64 + l * 8);
            const uint4 uc = *(const uint4*)(H + (size_t)e4.z * 64 + l * 8);
            const uint4 ud = *(const uint4*)(H + (size_t)e4.w * 64 + l * 8);
            ACC8(ua) ACC8(ub) ACC8(uc) ACC8(ud)
        }
        for (; s < e2; ++s) {
            const uint4 ua = *(const uint4*)(H + (size_t)rs[s] * 64 + l * 8);
            ACC8(ua)
        }
        const float dd = dinv[d];
        const float4 cba = *(const float4*)(CB + l * 8);
        const float4 cbb = *(const float4*)(CB + l * 8 + 4);
        ov.x = (unsigned)f2bf(relu(dd * a0 + cba.x)) |
               ((unsigned)f2bf(relu(dd * a1 + cba.y)) << 16);
        ov.y = (unsigned)f2bf(relu(dd * a2 + cba.z)) |
               ((unsigned)f2bf(relu(dd * a3 + cba.w)) << 16);
        ov.z = (unsigned)f2bf(relu(dd * a4 + cbb.x)) |
               ((unsigned)f2bf(relu(dd * a5 + cbb.y)) << 16);
        ov.w = (unsigned)f2bf(relu(dd * a6 + cbb.z)) |
               ((unsigned)f2bf(relu(dd * a7 + cbb.w)) << 16);
    }
    *(uint4*)&x2s[di][l * 8] = ov;
    __syncthreads();

    // phase B: wave pairs: (wave>>1) = node half, (wave&1) = col half
    const int wave = tid >> 6;
    const int lane = tid & 63;
    const int quad = lane >> 4;
    const int lm = lane & 15;
    const int nh = (wave >> 1) * 16;
    const int cb4 = (wave & 1) * 4;
    const int n0 = blockIdx.x * 32 + nh;
    if (n0 >= N) return;
    const int nrow = min(n0 + lm, N - 1);

    f32x4 acc[4];
#pragma unroll
    for (int c = 0; c < 4; c++) acc[c] = (f32x4){0.f, 0.f, 0.f, 0.f};
#pragma unroll
    for (int kc = 0; kc < 4; kc++) {
        bf16x8 a;
        if (kc < 2) {
            a = *(const bf16x8*)(X1B + (size_t)nrow * 64 + kc * 32 + quad * 8);
        } else {
            a = *(const bf16x8*)&x2s[nh + lm][(kc - 2) * 32 + quad * 8];
        }
#pragma unroll
        for (int c = 0; c < 4; c++) {
            const bf16x8 b =
                *(const bf16x8*)(Wt + (size_t)((kc * 8 + cb4 + c) * 64 + lane) * 8);
            acc[c] = __builtin_amdgcn_mfma_f32_16x16x32_bf16(a, b, acc[c], 0, 0, 0);
        }
    }
    const int nb = n0 + quad * 4;
    if (cb4 == 0) {
#pragma unroll
        for (int c = 0; c < 4; c++) {
            const int col = c * 16 + lm;
            const float b = B1[col];
#pragma unroll
            for (int r = 0; r < 4; r++) {
                const int n = nb + r;
                if (n < N) X5B[(size_t)n * 64 + col] = f2bf(relu(acc[c][r] + b));
            }
        }
    } else {
        float dvv[4];
#pragma unroll
        for (int r = 0; r < 4; r++) dvv[r] = (nb + r < N) ? dinv[nb + r] : 0.f;
#pragma unroll
        for (int c = 0; c < 4; c++) {
            const int col = c * 16 + lm;
#pragma unroll
            for (int r = 0; r < 4; r++) {
                const int n = nb + r;
                if (n < N) H2[(size_t)n * 64 + col] = f2bf(acc[c][r] * dvv[r]);
            }
        }
    }
}

// ---- gather2 + fused combine/projections (x5 now bf16) ----
__global__ __launch_bounds__(256) void k_gather2(const int* __restrict__ start,
                                                 const int* __restrict__ degi,
                                                 const int* __restrict__ rs,
                                                 const unsigned short* __restrict__ H,
                                                 const float* __restrict__ dinv,
                                                 const float* __restrict__ CB,
                                                 const unsigned short* __restrict__ X5B,
                                                 const float* __restrict__ FC2W,
                                                 const float* __restrict__ FC2B,
                                                 const float* __restrict__ C3W,
                                                 const float* __restrict__ C3B,
                                                 float* __restrict__ H3,
                                                 float* __restrict__ OUT, int N) {
    const int l = threadIdx.x & 7;
    const int d = blockIdx.x * 32 + (threadIdx.x >> 3);
    if (d >= N) return;
    int s = start[d];
    const int e2 = s + degi[d];
    float a0 = 0.f, a1 = 0.f, a2 = 0.f, a3 = 0.f;
    float a4 = 0.f, a5 = 0.f, a6 = 0.f, a7 = 0.f;
    for (; s + 3 < e2; s += 4) {
        const int4 e4 = *(const int4*)(rs + s);
        const uint4 ua = *(const uint4*)(H + (size_t)e4.x * 64 + l * 8);
        const uint4 ub = *(const uint4*)(H + (size_t)e4.y * 64 + l * 8);
        const uint4 uc = *(const uint4*)(H + (size_t)e4.z * 64 + l * 8);
        const uint4 ud = *(const uint4*)(H + (size_t)e4.w * 64 + l * 8);
        ACC8(ua) ACC8(ub) ACC8(uc) ACC8(ud)
    }
    for (; s < e2; ++s) {
        const uint4 ua = *(const uint4*)(H + (size_t)rs[s] * 64 + l * 8);
        ACC8(ua)
    }
    const float dd = dinv[d];
    const float4 cba = *(const float4*)(CB + l * 8);
    const float4 cbb = *(const float4*)(CB + l * 8 + 4);
    const uint4 xv = *(const uint4*)(X5B + (size_t)d * 64 + l * 8);
    const float v0 = bflo(xv.x) + relu(dd * a0 + cba.x);
    const float v1 = bfhi(xv.x) + relu(dd * a1 + cba.y);
    const float v2 = bflo(xv.y) + relu(dd * a2 + cba.z);
    const float v3 = bfhi(xv.y) + relu(dd * a3 + cba.w);
    const float v4 = bflo(xv.z) + relu(dd * a4 + cbb.x);
    const float v5 = bfhi(xv.z) + relu(dd * a5 + cbb.y);
    const float v6 = bflo(xv.w) + relu(dd * a6 + cbb.z);
    const float v7 = bfhi(xv.w) + relu(dd * a7 + cbb.w);
    const float4 w9a = *(const float4*)(FC2W + l * 8);
    const float4 w9b = *(const float4*)(FC2W + l * 8 + 4);
    const float4 wXa = *(const float4*)(C3W + l * 8);
    const float4 wXb = *(const float4*)(C3W + l * 8 + 4);
    float p9 = v0 * w9a.x + v1 * w9a.y + v2 * w9a.z + v3 * w9a.w
             + v4 * w9b.x + v5 * w9b.y + v6 * w9b.z + v7 * w9b.w;
    float p10 = v0 * wXa.x + v1 * wXa.y + v2 * wXa.z + v3 * wXa.w
              + v4 * wXb.x + v5 * wXb.y + v6 * wXb.z + v7 * wXb.w;
#pragma unroll
    for (int m = 1; m < 8; m <<= 1) {
        p9 += __shfl_xor(p9, m, 64);
        p10 += __shfl_xor(p10, m, 64);
    }
    if (l == 0) {
        OUT[d] = p9 + FC2B[0] + C3B[0];
        H3[d] = p10 * dd;   // pre-scale by dinv[row] for gather1f
    }
}
#undef ACC8

// ---- final CSR gather, 1 feature (H3 pre-scaled; ×dinv[d] at end) ----
__global__ __launch_bounds__(256) void k_gather1f(const int* __restrict__ start,
                                                  const int* __restrict__ degi,
                                                  const int* __restrict__ rs,
                                                  const float* __restrict__ H3,
                                                  const float* __restrict__ dinv,
                                                  float* __restrict__ OUT, int N) {
    const int d = blockIdx.x * 256 + threadIdx.x;
    if (d >= N) return;
    int s = start[d];
    const int e2 = s + degi[d];
    float acc = 0.f;
    for (; s + 3 < e2; s += 4) {
        const int4 e4 = *(const int4*)(rs + s);
        acc += H3[e4.x] + H3[e4.y] + H3[e4.z] + H3[e4.w];
    }
    for (; s < e2; ++s) acc += H3[rs[s]];
    OUT[d] += acc * dinv[d];
}

extern "C" void kernel_launch(void* const* d_in, const int* in_sizes, int n_in,
                              void* d_out, int out_size, void* d_ws, size_t ws_size,
                              hipStream_t stream) {
    const float* x    = (const float*)d_in[0];
    const float* fcw  = (const float*)d_in[1];
    const float* fcb  = (const float*)d_in[2];
    const float* c1w  = (const float*)d_in[3];
    const float* c1b  = (const float*)d_in[4];
    const float* f1w  = (const float*)d_in[5];
    const float* f1b  = (const float*)d_in[6];
    const float* c2w  = (const float*)d_in[7];
    const float* c2b  = (const float*)d_in[8];
    const float* f2w  = (const float*)d_in[9];
    const float* f2b  = (const float*)d_in[10];
    const float* c3w  = (const float*)d_in[11];
    const float* c3b  = (const float*)d_in[12];
    const int*   ei   = (const int*)d_in[13];

    const int N = in_sizes[0] / IN_DIM;
    const int E = in_sizes[13] / 2;
    const int* row = ei;
    const int* col = ei + E;
    float* out = (float*)d_out;

    const int NR = (N + RB - 1) >> RB_SHIFT;

    const size_t Npad = ((size_t)N + 127) & ~(size_t)127;
    const size_t NF = (size_t)N * 64;
    const size_t REG = (size_t)NR * MAXBIN;
    int*   binCur = (int*)d_ws;                          // NBMAX
    int*   degi   = binCur + NBMAX;                      // N
    float* dinv   = (float*)(degi + Npad);               // N
    int*   start  = (int*)(dinv + Npad);                 // N
    unsigned short* Wt = (unsigned short*)(start + Npad);// 2*16384 bf16
    int*   part   = (int*)(Wt + 2 * 16384);              // REG int (packed)
    int*   rs     = part + REG;                          // REG int
    unsigned short* x1bf = (unsigned short*)(rs + REG);  // N*64 bf16
    unsigned short* h1   = x1bf + NF;                    // N*64 bf16
    unsigned short* h2   = h1 + NF;                      // N*64 bf16 (no alias: gfuse race)
    unsigned short* x5b  = h2 + NF;                      // N*64 bf16
    float* h3     = (float*)(x5b + NF);                  // N f32 (pre-scaled)

    const int gN = (N + 255) / 256;
    const int gG = (N + 63) / 64;
    const int gF = (N + 31) / 32;
    const int gP = (E + PCH - 1) / PCH;

    // --- CSR build + weight repack ---
    k_wprep<<<16, 256, 0, stream>>>(fcw, c1w, f1w, c2w, Wt, binCur, NR);
    k_part<<<gP, 256, 0, stream>>>(row, col, binCur, part, E);
    k_csr<<<NR, 256, 0, stream>>>(binCur, part, degi, dinv, start, rs, N);

    // --- layer 1 ---
    k_gemm1<<<gG, 256, 0, stream>>>(x, Wt, fcb, dinv, x1bf, h1, N);

    // --- gather1 + layer-2 GEMM fused ---
    k_gfuse<<<gF, 256, 0, stream>>>(start, degi, rs, h1, dinv, c1b,
                                    x1bf, Wt + 16384, f1b, x5b, h2, N);

    // --- layer 3 (combine fused into gather2) ---
    k_gather2<<<gF, 256, 0, stream>>>(start, degi, rs, h2, dinv, c2b, x5b,
                                      f2w, f2b, c3w, c3b, h3, out, N);
    k_gather1f<<<gN, 256, 0, stream>>>(start, degi, rs, h3, dinv, out, N);
}